// Round 1
// baseline (562.636 us; speedup 1.0000x reference)
//
#include <hip/hip_runtime.h>
#include <hip/hip_bf16.h>
#include <stdint.h>
#include <stddef.h>

typedef __bf16 bf16_t;
typedef __bf16 bf16x4 __attribute__((ext_vector_type(4)));
typedef __bf16 bf16x8 __attribute__((ext_vector_type(8)));
typedef float  f32x4  __attribute__((ext_vector_type(4)));

#define Bsz  4
#define Ssz  2048
#define Dsz  768
#define Isz  1536
#define Hn   8
#define HDsz 64
#define NTOK (Bsz*Ssz)      /* 8192 */
#define Lc   64
#define NCH  (Ssz/Lc)       /* 32 */
#define NBH  (Bsz*Hn)       /* 32 */

/* ---------------- workspace layout (bytes) ---------------- */
#define OFF_H      ((size_t)0)                        /* 8192*768*2  (reused: og) */
#define OFF_WUPT   ((size_t)12582912)
#define OFF_WQT    (OFF_WUPT   + 2359296)
#define OFF_WKT    (OFF_WQT    + 1572864)
#define OFF_WVT    (OFF_WKT    + 1572864)
#define OFF_WOT    (OFF_WVT    + 1572864)
#define OFF_WOUTT  (OFF_WOT    + 1572864)
#define OFF_WDOWNT (OFF_WOUTT  + 1572864)
#define OFF_U      (OFF_WDOWNT + 2359296)             /* 8192*1536*2 (reused: gated) */
#define OFF_Q      (OFF_U      + 25165824)            /* q,k,v region reused for y */
#define OFF_K      (OFF_Q      + 8388608)
#define OFF_V      (OFF_K      + 8388608)
#define OFF_IFB    (OFF_V      + 8388608)             /* 8192*16*4 */
#define OFF_BLOC   (OFF_IFB    + 524288)              /* 32*2048*4 */
#define OFF_MHAT   (OFF_BLOC   + 262144)
#define OFF_MST    (OFF_MHAT   + 262144)              /* 32*32*4 */
#define OFF_CST    (OFF_MST    + 4096)                /* 32*32*64*64*4 */
#define OFF_NST    (OFF_CST    + 16777216)            /* 32*32*64*4 */
#define OFF_HT     (OFF_NST    + 262144)              /* 8192*512*4 */
#define OFF_OG     OFF_H
#define OFF_G      OFF_U
#define OFF_Y      OFF_Q

/* ---------------- helpers ---------------- */
__device__ __forceinline__ void gload16(const void* gsrc, void* ldst) {
  __builtin_amdgcn_global_load_lds(
      (const __attribute__((address_space(1))) void*)gsrc,
      (__attribute__((address_space(3))) void*)ldst, 16, 0, 0);
}

__device__ __forceinline__ float blockReduceSum256(float v) {
  #pragma unroll
  for (int o = 1; o < 64; o <<= 1) v += __shfl_xor(v, o, 64);
  __shared__ float sh[4];
  int wid = threadIdx.x >> 6;
  __syncthreads();
  if ((threadIdx.x & 63) == 0) sh[wid] = v;
  __syncthreads();
  return sh[0] + sh[1] + sh[2] + sh[3];
}

/* ---------------- weight transpose+cast: W (K,N) f32 -> Wt (N,K) bf16 ---------------- */
__global__ __launch_bounds__(256) void transpose_cast(const float* __restrict__ W,
                                                      bf16_t* __restrict__ Wt,
                                                      int K, int N) {
  __shared__ float tile[32][33];
  int n0 = blockIdx.x * 32, k0 = blockIdx.y * 32;
  int tx = threadIdx.x, ty = threadIdx.y;   /* block (32,8) */
  #pragma unroll
  for (int j = 0; j < 32; j += 8)
    tile[ty + j][tx] = W[(size_t)(k0 + ty + j) * N + n0 + tx];
  __syncthreads();
  #pragma unroll
  for (int j = 0; j < 32; j += 8)
    Wt[(size_t)(n0 + ty + j) * K + k0 + tx] = (bf16_t)tile[tx][ty + j];
}

/* ---------------- LayerNorm: x f32 (tok,768) -> h bf16 ---------------- */
__global__ __launch_bounds__(256) void ln_kernel(const float* __restrict__ x,
                                                 const float* __restrict__ g,
                                                 const float* __restrict__ bta,
                                                 bf16_t* __restrict__ h) {
  size_t tok = blockIdx.x;
  const float* xr = x + tok * Dsz;
  int t = threadIdx.x;
  float v[3]; float s = 0.f;
  #pragma unroll
  for (int i = 0; i < 3; ++i) { v[i] = xr[t + 256 * i]; s += v[i]; }
  s = blockReduceSum256(s);
  float mu = s * (1.f / Dsz);
  float s2 = 0.f;
  #pragma unroll
  for (int i = 0; i < 3; ++i) { float d = v[i] - mu; s2 += d * d; }
  s2 = blockReduceSum256(s2);
  float rs = rsqrtf(s2 * (1.f / Dsz) + 1e-5f);
  #pragma unroll
  for (int i = 0; i < 3; ++i) {
    int col = t + 256 * i;
    h[tok * Dsz + col] = (bf16_t)((v[i] - mu) * rs * g[col] + bta[col]);
  }
}

/* ---------------- bf16 MFMA GEMM: C(M,N) = A(M,K) @ Bt(N,K)^T  ---------------- */
/* EPI: 0 = bf16 out; 1 = bf16 out * scale; 2 = sigmoid(acc + bias[col]) bf16 out;
        3 = f32 out = acc + resid[row*N+col] */
template<int EPI>
__global__ __launch_bounds__(256) void gemm_bt(const bf16_t* __restrict__ A,
                                               const bf16_t* __restrict__ Bt,
                                               void* __restrict__ Cout,
                                               const void* __restrict__ extra,
                                               int M, int N, int K, float scale) {
  __shared__ bf16_t As[128 * 64];
  __shared__ bf16_t Bs[128 * 64];
  const int t = threadIdx.x;
  const int w = t >> 6, l = t & 63;
  const int tile_m = blockIdx.y * 128, tile_n = blockIdx.x * 128;
  const int wr = w >> 1, wc = w & 1;
  const int lrow = l >> 3, lk = (l & 7) * 8;
  const int l15 = l & 15, l4 = l >> 4;

  f32x4 acc[4][4];
  f32x4 zero = {0.f, 0.f, 0.f, 0.f};
  #pragma unroll
  for (int m = 0; m < 4; ++m)
    #pragma unroll
    for (int n = 0; n < 4; ++n) acc[m][n] = zero;

  for (int k0 = 0; k0 < K; k0 += 64) {
    #pragma unroll
    for (int i = 0; i < 4; ++i) {
      int ch = w * 4 + i;
      int row = ch * 8 + lrow;
      const bf16_t* ga = A  + (size_t)(tile_m + row) * K + k0 + lk;
      const bf16_t* gb = Bt + (size_t)(tile_n + row) * K + k0 + lk;
      gload16(ga, &As[ch * 512]);
      gload16(gb, &Bs[ch * 512]);
    }
    __syncthreads();
    #pragma unroll
    for (int kk = 0; kk < 2; ++kk) {
      bf16x8 af[4], bfr[4];
      #pragma unroll
      for (int m = 0; m < 4; ++m)
        af[m] = *(const bf16x8*)&As[(wr * 64 + m * 16 + l15) * 64 + kk * 32 + l4 * 8];
      #pragma unroll
      for (int n = 0; n < 4; ++n)
        bfr[n] = *(const bf16x8*)&Bs[(wc * 64 + n * 16 + l15) * 64 + kk * 32 + l4 * 8];
      #pragma unroll
      for (int m = 0; m < 4; ++m)
        #pragma unroll
        for (int n = 0; n < 4; ++n)
          acc[m][n] = __builtin_amdgcn_mfma_f32_16x16x32_bf16(af[m], bfr[n], acc[m][n], 0, 0, 0);
    }
    __syncthreads();
  }

  const int rbase = tile_m + wr * 64 + l4 * 4;
  const int cbase = tile_n + wc * 64 + l15;
  #pragma unroll
  for (int m = 0; m < 4; ++m)
    #pragma unroll
    for (int n = 0; n < 4; ++n)
      #pragma unroll
      for (int j = 0; j < 4; ++j) {
        int row = rbase + m * 16 + j;
        int col = cbase + n * 16;
        float v = acc[m][n][j];
        if constexpr (EPI == 0) {
          ((bf16_t*)Cout)[(size_t)row * N + col] = (bf16_t)v;
        } else if constexpr (EPI == 1) {
          ((bf16_t*)Cout)[(size_t)row * N + col] = (bf16_t)(v * scale);
        } else if constexpr (EPI == 2) {
          float z = v + ((const float*)extra)[col];
          float sg = 1.f / (1.f + __expf(-z));
          ((bf16_t*)Cout)[(size_t)row * N + col] = (bf16_t)sg;
        } else {
          ((float*)Cout)[(size_t)row * N + col] =
              v + ((const float*)extra)[(size_t)row * N + col];
        }
      }
}

/* ---------------- i/f gate projections: u (tok,1536) bf16 -> ifb (tok,16) f32 ---------------- */
__global__ __launch_bounds__(256) void ifproj(const bf16_t* __restrict__ u,
                                              const float* __restrict__ Wi,
                                              const float* __restrict__ bi,
                                              const float* __restrict__ Wf,
                                              const float* __restrict__ bfv,
                                              float* __restrict__ ifb) {
  size_t tok = blockIdx.x;
  int t = threadIdx.x;
  const bf16_t* ur = u + tok * Isz;
  float acc[16];
  #pragma unroll
  for (int j = 0; j < 16; ++j) acc[j] = 0.f;
  for (int k = t; k < Isz; k += 256) {
    float uv = (float)ur[k];
    f32x4 wi0 = *(const f32x4*)&Wi[(size_t)k * 8];
    f32x4 wi1 = *(const f32x4*)&Wi[(size_t)k * 8 + 4];
    f32x4 wf0 = *(const f32x4*)&Wf[(size_t)k * 8];
    f32x4 wf1 = *(const f32x4*)&Wf[(size_t)k * 8 + 4];
    #pragma unroll
    for (int j = 0; j < 4; ++j) {
      acc[j]      += uv * wi0[j];
      acc[4 + j]  += uv * wi1[j];
      acc[8 + j]  += uv * wf0[j];
      acc[12 + j] += uv * wf1[j];
    }
  }
  #pragma unroll
  for (int j = 0; j < 16; ++j)
    #pragma unroll
    for (int o = 1; o < 64; o <<= 1) acc[j] += __shfl_xor(acc[j], o, 64);
  __shared__ float red[4][16];
  int wid = t >> 6, lane = t & 63;
  if (lane == 0)
    #pragma unroll
    for (int j = 0; j < 16; ++j) red[wid][j] = acc[j];
  __syncthreads();
  if (t < 16) {
    float s = red[0][t] + red[1][t] + red[2][t] + red[3][t];
    s += (t < 8) ? bi[t] : bfv[t - 8];
    ifb[tok * 16 + t] = s;
  }
}

/* ---------------- gates pass A: per (bh,chunk) local cumsum + prefix-max ---------------- */
__global__ __launch_bounds__(64) void gates_a(const float* __restrict__ ifb,
                                              float* __restrict__ blocal,
                                              float* __restrict__ Mhat) {
  int bh = blockIdx.x >> 5, c = blockIdx.x & 31;
  int b = bh >> 3, h = bh & 7;
  int lane = threadIdx.x;
  size_t tok = (size_t)b * Ssz + c * Lc + lane;
  float iv = ifb[tok * 16 + h];
  float fv = ifb[tok * 16 + 8 + h];
  float bt = fv;
  #pragma unroll
  for (int d = 1; d < 64; d <<= 1) { float o = __shfl_up(bt, d, 64); if (lane >= d) bt += o; }
  float a = iv - bt;
  float pm = a;
  #pragma unroll
  for (int d = 1; d < 64; d <<= 1) { float o = __shfl_up(pm, d, 64); if (lane >= d) pm = fmaxf(pm, o); }
  blocal[(size_t)bh * Ssz + c * Lc + lane] = bt;
  Mhat[(size_t)bh * Ssz + c * Lc + lane] = bt + pm;
}

/* ---------------- gates pass B: sequential chunk-boundary m recurrence ---------------- */
__global__ void gates_b(const float* __restrict__ blocal, const float* __restrict__ Mhat,
                        float* __restrict__ mstart) {
  int bh = threadIdx.x;
  if (bh < NBH) {
    float M = 0.f;
    for (int c = 0; c < NCH; ++c) {
      mstart[bh * NCH + c] = M;
      float bL = blocal[(size_t)bh * Ssz + c * Lc + 63];
      float Mh = Mhat[(size_t)bh * Ssz + c * Lc + 63];
      M = fmaxf(M + bL, Mh);
    }
  }
}

/* ---------------- chunk-state recurrence: per (b,h), sequential over chunks ---------------- */
__global__ __launch_bounds__(256) void chunk_state(const bf16_t* __restrict__ kb,
                                                   const bf16_t* __restrict__ vb,
                                                   const float* __restrict__ ifb,
                                                   const float* __restrict__ blocal,
                                                   const float* __restrict__ Mhat,
                                                   float* __restrict__ Cst,
                                                   float* __restrict__ nst) {
  int bh = blockIdx.x;
  int b = bh >> 3, h = bh & 7;
  __shared__ float Kl[64][64];
  __shared__ float Vl[64][64];
  __shared__ float wsh[64];
  int t = threadIdx.x;
  int tv = t >> 4, tk = t & 15;
  float Creg[16];
  #pragma unroll
  for (int i = 0; i < 16; ++i) Creg[i] = 0.f;
  float nreg = 0.f;
  float Mc = 0.f;

  for (int c = 0; c < NCH; ++c) {
    size_t sb = (size_t)bh * NCH + c;
    /* store state entering chunk c */
    #pragma unroll
    for (int i = 0; i < 4; ++i)
      #pragma unroll
      for (int j = 0; j < 4; ++j)
        Cst[sb * 4096 + (size_t)(4 * tv + i) * 64 + 4 * tk + j] = Creg[i * 4 + j];
    if (t < 64) nst[sb * 64 + t] = nreg;

    float bL = blocal[(size_t)bh * Ssz + c * Lc + 63];
    float Mh = Mhat[(size_t)bh * Ssz + c * Lc + 63];
    float mL = fmaxf(Mc + bL, Mh);
    float decay = __expf(Mc + bL - mL);

    if (t < 64) {
      float bt = blocal[(size_t)bh * Ssz + c * Lc + t];
      float iv = ifb[((size_t)b * Ssz + c * Lc + t) * 16 + h];
      wsh[t] = __expf(iv + bL - bt - mL);
    }
    for (int idx = t; idx < 4096; idx += 256) {
      int s = idx >> 6, d = idx & 63;
      size_t gi = (((size_t)b * Ssz + c * Lc + s) * Hn + h) * HDsz + d;
      Kl[s][d] = (float)kb[gi];
      Vl[s][d] = (float)vb[gi];
    }
    __syncthreads();

    #pragma unroll
    for (int i = 0; i < 16; ++i) Creg[i] *= decay;
    for (int s = 0; s < 64; ++s) {
      float ws = wsh[s];
      f32x4 kv = *(const f32x4*)&Kl[s][4 * tk];
      f32x4 vv = *(const f32x4*)&Vl[s][4 * tv];
      float wv0 = ws * vv[0], wv1 = ws * vv[1], wv2 = ws * vv[2], wv3 = ws * vv[3];
      Creg[0]  += wv0 * kv[0]; Creg[1]  += wv0 * kv[1]; Creg[2]  += wv0 * kv[2]; Creg[3]  += wv0 * kv[3];
      Creg[4]  += wv1 * kv[0]; Creg[5]  += wv1 * kv[1]; Creg[6]  += wv1 * kv[2]; Creg[7]  += wv1 * kv[3];
      Creg[8]  += wv2 * kv[0]; Creg[9]  += wv2 * kv[1]; Creg[10] += wv2 * kv[2]; Creg[11] += wv2 * kv[3];
      Creg[12] += wv3 * kv[0]; Creg[13] += wv3 * kv[1]; Creg[14] += wv3 * kv[2]; Creg[15] += wv3 * kv[3];
    }
    if (t < 64) {
      nreg *= decay;
      for (int s = 0; s < 64; ++s) nreg += wsh[s] * Kl[s][t];
    }
    Mc = mL;
    __syncthreads();
  }
}

/* ---------------- intra-chunk outputs: fully parallel over (bh,chunk) ---------------- */
__global__ __launch_bounds__(256) void intra(const bf16_t* __restrict__ qb,
                                             const bf16_t* __restrict__ kb,
                                             const bf16_t* __restrict__ vb,
                                             const float* __restrict__ ifb,
                                             const float* __restrict__ blocal,
                                             const float* __restrict__ Mhat,
                                             const float* __restrict__ mstart,
                                             const float* __restrict__ Cst,
                                             const float* __restrict__ nst,
                                             float* __restrict__ ht) {
  int bh = blockIdx.x >> 5, c = blockIdx.x & 31;
  int b = bh >> 3, h = bh & 7;
  __shared__ bf16_t qT[64][68];
  __shared__ bf16_t kT[64][68];
  __shared__ bf16_t vL[64][64];
  __shared__ float  PT[64][65];
  __shared__ float  CT[64][68];
  __shared__ float  nin[64], den[64], ssrc[64], sdst[64], esc[64];
  int t = threadIdx.x;
  size_t tok0 = (size_t)b * Ssz + c * Lc;
  size_t cbase = ((size_t)bh * NCH + c) * 4096;

  for (int idx = t; idx < 4096; idx += 256) {
    int r = idx >> 6, d = idx & 63;
    size_t gi = ((tok0 + r) * Hn + h) * HDsz + d;
    qT[d][r] = qb[gi];
    kT[d][r] = kb[gi];
    vL[r][d] = vb[gi];
    CT[d][r] = Cst[cbase + idx];   /* C[v=r][k=d] -> CT[k][v] */
  }
  if (t < 64) {
    nin[t] = nst[((size_t)bh * NCH + c) * 64 + t];
    float bt = blocal[(size_t)bh * Ssz + c * Lc + t];
    float Mh = Mhat[(size_t)bh * Ssz + c * Lc + t];
    float Mc = mstart[bh * NCH + c];
    float iv = ifb[(tok0 + t) * 16 + h];
    float mt = fmaxf(Mc + bt, Mh);
    ssrc[t] = iv - bt;
    sdst[t] = bt - mt;
    esc[t]  = __expf(Mc + bt - mt);
    den[t]  = 0.f;
  }
  __syncthreads();

  const int tr4 = 4 * (t >> 4), tc4 = 4 * (t & 15);

  /* Step A: raw scores q.k */
  float acc[16];
  #pragma unroll
  for (int i = 0; i < 16; ++i) acc[i] = 0.f;
  for (int d = 0; d < 64; ++d) {
    bf16x4 qv = *(const bf16x4*)&qT[d][tr4];
    bf16x4 kv = *(const bf16x4*)&kT[d][tc4];
    float q0 = (float)qv[0], q1 = (float)qv[1], q2 = (float)qv[2], q3 = (float)qv[3];
    float k0 = (float)kv[0], k1 = (float)kv[1], k2 = (float)kv[2], k3 = (float)kv[3];
    acc[0]  += q0 * k0; acc[1]  += q0 * k1; acc[2]  += q0 * k2; acc[3]  += q0 * k3;
    acc[4]  += q1 * k0; acc[5]  += q1 * k1; acc[6]  += q1 * k2; acc[7]  += q1 * k3;
    acc[8]  += q2 * k0; acc[9]  += q2 * k1; acc[10] += q2 * k2; acc[11] += q2 * k3;
    acc[12] += q3 * k0; acc[13] += q3 * k1; acc[14] += q3 * k2; acc[15] += q3 * k3;
  }
  /* decay-mask weights, write P^T, row-sum partials */
  #pragma unroll
  for (int i = 0; i < 4; ++i) {
    int tau = tr4 + i;
    float sd = sdst[tau];
    float rs = 0.f;
    #pragma unroll
    for (int j = 0; j < 4; ++j) {
      int sg = tc4 + j;
      float p = (sg <= tau) ? acc[i * 4 + j] * __expf(ssrc[sg] + sd) : 0.f;
      PT[sg][tau] = p;
      rs += p;
    }
    atomicAdd(&den[tau], rs);
  }
  __syncthreads();
  if (t < 64) {
    float nq = 0.f;
    for (int k2 = 0; k2 < 64; ++k2) nq += nin[k2] * (float)qT[k2][t];
    float tot = den[t] + esc[t] * nq;
    den[t] = fmaxf(fabsf(tot), 1.0f);
  }
  __syncthreads();

  /* Step B: PV + inter-chunk C_in q */
  float aPV[16], aCq[16];
  #pragma unroll
  for (int i = 0; i < 16; ++i) { aPV[i] = 0.f; aCq[i] = 0.f; }
  for (int s = 0; s < 64; ++s) {
    float p0 = PT[s][tr4], p1 = PT[s][tr4 + 1], p2 = PT[s][tr4 + 2], p3 = PT[s][tr4 + 3];
    bf16x4 vv4 = *(const bf16x4*)&vL[s][tc4];
    float v0 = (float)vv4[0], v1 = (float)vv4[1], v2 = (float)vv4[2], v3 = (float)vv4[3];
    aPV[0]  += p0 * v0; aPV[1]  += p0 * v1; aPV[2]  += p0 * v2; aPV[3]  += p0 * v3;
    aPV[4]  += p1 * v0; aPV[5]  += p1 * v1; aPV[6]  += p1 * v2; aPV[7]  += p1 * v3;
    aPV[8]  += p2 * v0; aPV[9]  += p2 * v1; aPV[10] += p2 * v2; aPV[11] += p2 * v3;
    aPV[12] += p3 * v0; aPV[13] += p3 * v1; aPV[14] += p3 * v2; aPV[15] += p3 * v3;
    bf16x4 qv4 = *(const bf16x4*)&qT[s][tr4];
    f32x4 cv = *(const f32x4*)&CT[s][tc4];
    float q0 = (float)qv4[0], q1 = (float)qv4[1], q2 = (float)qv4[2], q3 = (float)qv4[3];
    aCq[0]  += q0 * cv[0]; aCq[1]  += q0 * cv[1]; aCq[2]  += q0 * cv[2]; aCq[3]  += q0 * cv[3];
    aCq[4]  += q1 * cv[0]; aCq[5]  += q1 * cv[1]; aCq[6]  += q1 * cv[2]; aCq[7]  += q1 * cv[3];
    aCq[8]  += q2 * cv[0]; aCq[9]  += q2 * cv[1]; aCq[10] += q2 * cv[2]; aCq[11] += q2 * cv[3];
    aCq[12] += q3 * cv[0]; aCq[13] += q3 * cv[1]; aCq[14] += q3 * cv[2]; aCq[15] += q3 * cv[3];
  }
  #pragma unroll
  for (int i = 0; i < 4; ++i) {
    int tau = tr4 + i;
    float e = esc[tau], dn = den[tau];
    size_t rowg = ((tok0 + tau) * Hn + h) * HDsz;
    #pragma unroll
    for (int j = 0; j < 4; ++j)
      ht[rowg + tc4 + j] = (aPV[i * 4 + j] + e * aCq[i * 4 + j]) / dn;
  }
}

/* ---------------- group-norm + output gate: gated = sigmoid(og)*GN(ht)*mh_g ---------------- */
__global__ __launch_bounds__(256) void gn_gate(const float* __restrict__ ht,
                                               const bf16_t* __restrict__ og,
                                               const float* __restrict__ mhg,
                                               bf16_t* __restrict__ gated) {
  int gid = blockIdx.x * 4 + (threadIdx.x >> 6);   /* (b*S+s)*8+h */
  int lane = threadIdx.x & 63;
  int h = gid & 7;
  size_t idx = (size_t)gid * 64 + lane;
  float v = ht[idx];
  float s = v;
  #pragma unroll
  for (int o = 1; o < 64; o <<= 1) s += __shfl_xor(s, o, 64);
  float mu = s * (1.f / 64.f);
  float d = v - mu;
  float s2 = d * d;
  #pragma unroll
  for (int o = 1; o < 64; o <<= 1) s2 += __shfl_xor(s2, o, 64);
  float hn = d * rsqrtf(s2 * (1.f / 64.f) + 1e-5f) * mhg[h * 64 + lane];
  gated[idx] = (bf16_t)((float)og[idx] * hn);
}

/* ---------------- launcher ---------------- */
extern "C" void kernel_launch(void* const* d_in, const int* in_sizes, int n_in,
                              void* d_out, int out_size, void* d_ws, size_t ws_size,
                              hipStream_t stream) {
  const float* x     = (const float*)d_in[0];
  const float* ln_g  = (const float*)d_in[1];
  const float* ln_b  = (const float*)d_in[2];
  const float* W_up  = (const float*)d_in[3];
  const float* W_down= (const float*)d_in[4];
  const float* Wq    = (const float*)d_in[5];
  const float* Wk    = (const float*)d_in[6];
  const float* Wv    = (const float*)d_in[7];
  const float* Wi    = (const float*)d_in[8];
  const float* bi    = (const float*)d_in[9];
  const float* Wf    = (const float*)d_in[10];
  const float* bfv   = (const float*)d_in[11];
  const float* Wo    = (const float*)d_in[12];
  const float* bo    = (const float*)d_in[13];
  const float* mh_g  = (const float*)d_in[14];
  const float* W_out = (const float*)d_in[15];

  char* ws = (char*)d_ws;
  bf16_t* hbuf   = (bf16_t*)(ws + OFF_H);
  bf16_t* wupT   = (bf16_t*)(ws + OFF_WUPT);
  bf16_t* wqT    = (bf16_t*)(ws + OFF_WQT);
  bf16_t* wkT    = (bf16_t*)(ws + OFF_WKT);
  bf16_t* wvT    = (bf16_t*)(ws + OFF_WVT);
  bf16_t* woT    = (bf16_t*)(ws + OFF_WOT);
  bf16_t* woutT  = (bf16_t*)(ws + OFF_WOUTT);
  bf16_t* wdownT = (bf16_t*)(ws + OFF_WDOWNT);
  bf16_t* ubuf   = (bf16_t*)(ws + OFF_U);
  bf16_t* qbuf   = (bf16_t*)(ws + OFF_Q);
  bf16_t* kbuf   = (bf16_t*)(ws + OFF_K);
  bf16_t* vbuf   = (bf16_t*)(ws + OFF_V);
  float*  ifb    = (float*)(ws + OFF_IFB);
  float*  bloc   = (float*)(ws + OFF_BLOC);
  float*  Mh     = (float*)(ws + OFF_MHAT);
  float*  mst    = (float*)(ws + OFF_MST);
  float*  Cst    = (float*)(ws + OFF_CST);
  float*  nst    = (float*)(ws + OFF_NST);
  float*  htbuf  = (float*)(ws + OFF_HT);
  bf16_t* ogbuf  = (bf16_t*)(ws + OFF_OG);
  bf16_t* gbuf   = (bf16_t*)(ws + OFF_G);
  bf16_t* ybuf   = (bf16_t*)(ws + OFF_Y);

  dim3 tb(32, 8);
  transpose_cast<<<dim3(Isz / 32, Dsz / 32), tb, 0, stream>>>(W_up, wupT, Dsz, Isz);
  transpose_cast<<<dim3(512 / 32, Isz / 32), tb, 0, stream>>>(Wq, wqT, Isz, 512);
  transpose_cast<<<dim3(512 / 32, Isz / 32), tb, 0, stream>>>(Wk, wkT, Isz, 512);
  transpose_cast<<<dim3(512 / 32, Isz / 32), tb, 0, stream>>>(Wv, wvT, Isz, 512);
  transpose_cast<<<dim3(512 / 32, Isz / 32), tb, 0, stream>>>(Wo, woT, Isz, 512);
  transpose_cast<<<dim3(Isz / 32, 512 / 32), tb, 0, stream>>>(W_out, woutT, 512, Isz);
  transpose_cast<<<dim3(Dsz / 32, Isz / 32), tb, 0, stream>>>(W_down, wdownT, Isz, Dsz);

  ln_kernel<<<NTOK, 256, 0, stream>>>(x, ln_g, ln_b, hbuf);

  gemm_bt<0><<<dim3(Isz / 128, NTOK / 128), 256, 0, stream>>>(hbuf, wupT, ubuf, nullptr, NTOK, Isz, Dsz, 1.f);
  gemm_bt<0><<<dim3(512 / 128, NTOK / 128), 256, 0, stream>>>(ubuf, wqT, qbuf, nullptr, NTOK, 512, Isz, 1.f);
  gemm_bt<1><<<dim3(512 / 128, NTOK / 128), 256, 0, stream>>>(ubuf, wkT, kbuf, nullptr, NTOK, 512, Isz, 0.125f);
  gemm_bt<0><<<dim3(512 / 128, NTOK / 128), 256, 0, stream>>>(ubuf, wvT, vbuf, nullptr, NTOK, 512, Isz, 1.f);

  ifproj<<<NTOK, 256, 0, stream>>>(ubuf, Wi, bi, Wf, bfv, ifb);
  gates_a<<<NBH * NCH, 64, 0, stream>>>(ifb, bloc, Mh);
  gates_b<<<1, 32, 0, stream>>>(bloc, Mh, mst);
  chunk_state<<<NBH, 256, 0, stream>>>(kbuf, vbuf, ifb, bloc, Mh, Cst, nst);
  intra<<<NBH * NCH, 256, 0, stream>>>(qbuf, kbuf, vbuf, ifb, bloc, Mh, mst, Cst, nst, htbuf);

  gemm_bt<2><<<dim3(512 / 128, NTOK / 128), 256, 0, stream>>>(ubuf, woT, ogbuf, bo, NTOK, 512, Isz, 1.f);
  gn_gate<<<NTOK * Hn / 4, 256, 0, stream>>>(htbuf, ogbuf, mh_g, gbuf);
  gemm_bt<0><<<dim3(Isz / 128, NTOK / 128), 256, 0, stream>>>(gbuf, woutT, ybuf, nullptr, NTOK, Isz, 512, 1.f);
  gemm_bt<3><<<dim3(Dsz / 128, NTOK / 128), 256, 0, stream>>>(ybuf, wdownT, (float*)d_out, x, NTOK, Dsz, Isz, 1.f);
}

// Round 2
// 408.716 us; speedup vs baseline: 1.3766x; 1.3766x over previous
//
#include <hip/hip_runtime.h>
#include <hip/hip_bf16.h>
#include <stdint.h>
#include <stddef.h>

typedef __bf16 bf16_t;
typedef __bf16 bf16x4 __attribute__((ext_vector_type(4)));
typedef __bf16 bf16x8 __attribute__((ext_vector_type(8)));
typedef float  f32x4  __attribute__((ext_vector_type(4)));

#define Bsz  4
#define Ssz  2048
#define Dsz  768
#define Isz  1536
#define Hn   8
#define HDsz 64
#define NTOK (Bsz*Ssz)      /* 8192 */
#define Lc   64
#define NCH  (Ssz/Lc)       /* 32 */
#define NBH  (Bsz*Hn)       /* 32 */

/* ---------------- workspace layout (bytes) ---------------- */
#define OFF_H      ((size_t)0)                        /* 8192*768*2  (reused: og) */
#define OFF_WUPT   ((size_t)12582912)
#define OFF_WQT    (OFF_WUPT   + 2359296)
#define OFF_WKT    (OFF_WQT    + 1572864)
#define OFF_WVT    (OFF_WKT    + 1572864)
#define OFF_WOT    (OFF_WVT    + 1572864)
#define OFF_WOUTT  (OFF_WOT    + 1572864)
#define OFF_WDOWNT (OFF_WOUTT  + 1572864)
#define OFF_U      (OFF_WDOWNT + 2359296)             /* 8192*1536*2 (reused: gated) */
#define OFF_Q      (OFF_U      + 25165824)            /* q,k,v region reused for y */
#define OFF_K      (OFF_Q      + 8388608)
#define OFF_V      (OFF_K      + 8388608)
#define OFF_IFB    (OFF_V      + 8388608)             /* 8192*16*4 */
#define OFF_BLOC   (OFF_IFB    + 524288)              /* 32*2048*4 */
#define OFF_MHAT   (OFF_BLOC   + 262144)
#define OFF_MST    (OFF_MHAT   + 262144)              /* 32*32*4 */
#define OFF_CST    (OFF_MST    + 4096)                /* 32*32*64*64*4 */
#define OFF_NST    (OFF_CST    + 16777216)            /* 32*32*64*4 */
#define OFF_HT     (OFF_NST    + 262144)              /* 8192*512*4 */
#define OFF_NG     (OFF_HT     + 16777216)            /* 32*32*64*4 */
#define OFF_DEC    (OFF_NG     + 262144)              /* 32*32*4 */
#define OFF_MEND   (OFF_DEC    + 4096)                /* 32*32*4 */
#define OFF_OG     OFF_H
#define OFF_G      OFF_U
#define OFF_Y      OFF_Q
#define OFF_GINC   OFF_HT   /* G increments alias ht: consumed by state_scan before intra writes ht */

/* ---------------- helpers ---------------- */
__device__ __forceinline__ void gload16(const void* gsrc, void* ldst) {
  __builtin_amdgcn_global_load_lds(
      (const __attribute__((address_space(1))) void*)gsrc,
      (__attribute__((address_space(3))) void*)ldst, 16, 0, 0);
}

__device__ __forceinline__ float blockReduceSum256(float v) {
  #pragma unroll
  for (int o = 1; o < 64; o <<= 1) v += __shfl_xor(v, o, 64);
  __shared__ float sh[4];
  int wid = threadIdx.x >> 6;
  __syncthreads();
  if ((threadIdx.x & 63) == 0) sh[wid] = v;
  __syncthreads();
  return sh[0] + sh[1] + sh[2] + sh[3];
}

/* ---------------- weight transpose+cast: W (K,N) f32 -> Wt (N,K) bf16 ---------------- */
__global__ __launch_bounds__(256) void transpose_cast(const float* __restrict__ W,
                                                      bf16_t* __restrict__ Wt,
                                                      int K, int N) {
  __shared__ float tile[32][33];
  int n0 = blockIdx.x * 32, k0 = blockIdx.y * 32;
  int tx = threadIdx.x, ty = threadIdx.y;   /* block (32,8) */
  #pragma unroll
  for (int j = 0; j < 32; j += 8)
    tile[ty + j][tx] = W[(size_t)(k0 + ty + j) * N + n0 + tx];
  __syncthreads();
  #pragma unroll
  for (int j = 0; j < 32; j += 8)
    Wt[(size_t)(n0 + ty + j) * K + k0 + tx] = (bf16_t)tile[tx][ty + j];
}

/* ---------------- LayerNorm: x f32 (tok,768) -> h bf16 ---------------- */
__global__ __launch_bounds__(256) void ln_kernel(const float* __restrict__ x,
                                                 const float* __restrict__ g,
                                                 const float* __restrict__ bta,
                                                 bf16_t* __restrict__ h) {
  size_t tok = blockIdx.x;
  const float* xr = x + tok * Dsz;
  int t = threadIdx.x;
  float v[3]; float s = 0.f;
  #pragma unroll
  for (int i = 0; i < 3; ++i) { v[i] = xr[t + 256 * i]; s += v[i]; }
  s = blockReduceSum256(s);
  float mu = s * (1.f / Dsz);
  float s2 = 0.f;
  #pragma unroll
  for (int i = 0; i < 3; ++i) { float d = v[i] - mu; s2 += d * d; }
  s2 = blockReduceSum256(s2);
  float rs = rsqrtf(s2 * (1.f / Dsz) + 1e-5f);
  #pragma unroll
  for (int i = 0; i < 3; ++i) {
    int col = t + 256 * i;
    h[tok * Dsz + col] = (bf16_t)((v[i] - mu) * rs * g[col] + bta[col]);
  }
}

/* ---------------- bf16 MFMA GEMM: C(M,N) = A(M,K) @ Bt(N,K)^T  ---------------- */
/* EPI: 0 = bf16 out; 1 = bf16 out * scale; 2 = sigmoid(acc + bias[col]) bf16 out;
        3 = f32 out = acc + resid[row*N+col] */
template<int EPI>
__global__ __launch_bounds__(256) void gemm_bt(const bf16_t* __restrict__ A,
                                               const bf16_t* __restrict__ Bt,
                                               void* __restrict__ Cout,
                                               const void* __restrict__ extra,
                                               int M, int N, int K, float scale) {
  __shared__ bf16_t As[128 * 64];
  __shared__ bf16_t Bs[128 * 64];
  const int t = threadIdx.x;
  const int w = t >> 6, l = t & 63;
  const int tile_m = blockIdx.y * 128, tile_n = blockIdx.x * 128;
  const int wr = w >> 1, wc = w & 1;
  const int lrow = l >> 3, lk = (l & 7) * 8;
  const int l15 = l & 15, l4 = l >> 4;

  f32x4 acc[4][4];
  f32x4 zero = {0.f, 0.f, 0.f, 0.f};
  #pragma unroll
  for (int m = 0; m < 4; ++m)
    #pragma unroll
    for (int n = 0; n < 4; ++n) acc[m][n] = zero;

  for (int k0 = 0; k0 < K; k0 += 64) {
    #pragma unroll
    for (int i = 0; i < 4; ++i) {
      int ch = w * 4 + i;
      int row = ch * 8 + lrow;
      const bf16_t* ga = A  + (size_t)(tile_m + row) * K + k0 + lk;
      const bf16_t* gb = Bt + (size_t)(tile_n + row) * K + k0 + lk;
      gload16(ga, &As[ch * 512]);
      gload16(gb, &Bs[ch * 512]);
    }
    __syncthreads();
    #pragma unroll
    for (int kk = 0; kk < 2; ++kk) {
      bf16x8 af[4], bfr[4];
      #pragma unroll
      for (int m = 0; m < 4; ++m)
        af[m] = *(const bf16x8*)&As[(wr * 64 + m * 16 + l15) * 64 + kk * 32 + l4 * 8];
      #pragma unroll
      for (int n = 0; n < 4; ++n)
        bfr[n] = *(const bf16x8*)&Bs[(wc * 64 + n * 16 + l15) * 64 + kk * 32 + l4 * 8];
      #pragma unroll
      for (int m = 0; m < 4; ++m)
        #pragma unroll
        for (int n = 0; n < 4; ++n)
          acc[m][n] = __builtin_amdgcn_mfma_f32_16x16x32_bf16(af[m], bfr[n], acc[m][n], 0, 0, 0);
    }
    __syncthreads();
  }

  const int rbase = tile_m + wr * 64 + l4 * 4;
  const int cbase = tile_n + wc * 64 + l15;
  #pragma unroll
  for (int m = 0; m < 4; ++m)
    #pragma unroll
    for (int n = 0; n < 4; ++n)
      #pragma unroll
      for (int j = 0; j < 4; ++j) {
        int row = rbase + m * 16 + j;
        int col = cbase + n * 16;
        float v = acc[m][n][j];
        if constexpr (EPI == 0) {
          ((bf16_t*)Cout)[(size_t)row * N + col] = (bf16_t)v;
        } else if constexpr (EPI == 1) {
          ((bf16_t*)Cout)[(size_t)row * N + col] = (bf16_t)(v * scale);
        } else if constexpr (EPI == 2) {
          float z = v + ((const float*)extra)[col];
          float sg = 1.f / (1.f + __expf(-z));
          ((bf16_t*)Cout)[(size_t)row * N + col] = (bf16_t)sg;
        } else {
          ((float*)Cout)[(size_t)row * N + col] =
              v + ((const float*)extra)[(size_t)row * N + col];
        }
      }
}

/* ---------------- i/f gate projections: u (tok,1536) bf16 -> ifb (tok,16) f32 ---------------- */
__global__ __launch_bounds__(256) void ifproj(const bf16_t* __restrict__ u,
                                              const float* __restrict__ Wi,
                                              const float* __restrict__ bi,
                                              const float* __restrict__ Wf,
                                              const float* __restrict__ bfv,
                                              float* __restrict__ ifb) {
  size_t tok = blockIdx.x;
  int t = threadIdx.x;
  const bf16_t* ur = u + tok * Isz;
  float acc[16];
  #pragma unroll
  for (int j = 0; j < 16; ++j) acc[j] = 0.f;
  for (int k = t; k < Isz; k += 256) {
    float uv = (float)ur[k];
    f32x4 wi0 = *(const f32x4*)&Wi[(size_t)k * 8];
    f32x4 wi1 = *(const f32x4*)&Wi[(size_t)k * 8 + 4];
    f32x4 wf0 = *(const f32x4*)&Wf[(size_t)k * 8];
    f32x4 wf1 = *(const f32x4*)&Wf[(size_t)k * 8 + 4];
    #pragma unroll
    for (int j = 0; j < 4; ++j) {
      acc[j]      += uv * wi0[j];
      acc[4 + j]  += uv * wi1[j];
      acc[8 + j]  += uv * wf0[j];
      acc[12 + j] += uv * wf1[j];
    }
  }
  #pragma unroll
  for (int j = 0; j < 16; ++j)
    #pragma unroll
    for (int o = 1; o < 64; o <<= 1) acc[j] += __shfl_xor(acc[j], o, 64);
  __shared__ float red[4][16];
  int wid = t >> 6, lane = t & 63;
  if (lane == 0)
    #pragma unroll
    for (int j = 0; j < 16; ++j) red[wid][j] = acc[j];
  __syncthreads();
  if (t < 16) {
    float s = red[0][t] + red[1][t] + red[2][t] + red[3][t];
    s += (t < 8) ? bi[t] : bfv[t - 8];
    ifb[tok * 16 + t] = s;
  }
}

/* ---------------- gates pass A: per (bh,chunk) local cumsum + prefix-max ---------------- */
__global__ __launch_bounds__(64) void gates_a(const float* __restrict__ ifb,
                                              float* __restrict__ blocal,
                                              float* __restrict__ Mhat) {
  int bh = blockIdx.x >> 5, c = blockIdx.x & 31;
  int b = bh >> 3, h = bh & 7;
  int lane = threadIdx.x;
  size_t tok = (size_t)b * Ssz + c * Lc + lane;
  float iv = ifb[tok * 16 + h];
  float fv = ifb[tok * 16 + 8 + h];
  float bt = fv;
  #pragma unroll
  for (int d = 1; d < 64; d <<= 1) { float o = __shfl_up(bt, d, 64); if (lane >= d) bt += o; }
  float a = iv - bt;
  float pm = a;
  #pragma unroll
  for (int d = 1; d < 64; d <<= 1) { float o = __shfl_up(pm, d, 64); if (lane >= d) pm = fmaxf(pm, o); }
  blocal[(size_t)bh * Ssz + c * Lc + lane] = bt;
  Mhat[(size_t)bh * Ssz + c * Lc + lane] = bt + pm;
}

/* ---------------- gates pass B: sequential chunk-boundary m recurrence + decays ---------------- */
__global__ void gates_b(const float* __restrict__ blocal, const float* __restrict__ Mhat,
                        float* __restrict__ mstart, float* __restrict__ decays,
                        float* __restrict__ mend) {
  int bh = threadIdx.x;
  if (bh < NBH) {
    float M = 0.f;
    for (int c = 0; c < NCH; ++c) {
      mstart[bh * NCH + c] = M;
      float bL = blocal[(size_t)bh * Ssz + c * Lc + 63];
      float Mh = Mhat[(size_t)bh * Ssz + c * Lc + 63];
      float Mn = fmaxf(M + bL, Mh);
      decays[bh * NCH + c] = __expf(M + bL - Mn);
      mend[bh * NCH + c] = Mn;
      M = Mn;
    }
  }
}

/* ---------------- per-chunk state increment (fully parallel over bh x chunk) ---------------- */
__global__ __launch_bounds__(256) void chunk_inc(const bf16_t* __restrict__ kb,
                                                 const bf16_t* __restrict__ vb,
                                                 const float* __restrict__ ifb,
                                                 const float* __restrict__ blocal,
                                                 const float* __restrict__ mend,
                                                 float* __restrict__ G,
                                                 float* __restrict__ ng) {
  int bh = blockIdx.x >> 5, c = blockIdx.x & 31;
  int b = bh >> 3, h = bh & 7;
  __shared__ float Kl[64][64];
  __shared__ float Vl[64][64];
  __shared__ float wsh[64];
  int t = threadIdx.x;
  int tv = t >> 4, tk = t & 15;
  float mL = mend[bh * NCH + c];
  float bL = blocal[(size_t)bh * Ssz + c * Lc + 63];

  if (t < 64) {
    float bt = blocal[(size_t)bh * Ssz + c * Lc + t];
    float iv = ifb[((size_t)b * Ssz + c * Lc + t) * 16 + h];
    wsh[t] = __expf(iv + bL - bt - mL);
  }
  for (int idx = t; idx < 4096; idx += 256) {
    int s = idx >> 6, d = idx & 63;
    size_t gi = (((size_t)b * Ssz + c * Lc + s) * Hn + h) * HDsz + d;
    Kl[s][d] = (float)kb[gi];
    Vl[s][d] = (float)vb[gi];
  }
  __syncthreads();

  float acc[16];
  #pragma unroll
  for (int i = 0; i < 16; ++i) acc[i] = 0.f;
  for (int s = 0; s < 64; ++s) {
    float ws = wsh[s];
    f32x4 kv = *(const f32x4*)&Kl[s][4 * tk];
    f32x4 vv = *(const f32x4*)&Vl[s][4 * tv];
    float wv0 = ws * vv[0], wv1 = ws * vv[1], wv2 = ws * vv[2], wv3 = ws * vv[3];
    acc[0]  += wv0 * kv[0]; acc[1]  += wv0 * kv[1]; acc[2]  += wv0 * kv[2]; acc[3]  += wv0 * kv[3];
    acc[4]  += wv1 * kv[0]; acc[5]  += wv1 * kv[1]; acc[6]  += wv1 * kv[2]; acc[7]  += wv1 * kv[3];
    acc[8]  += wv2 * kv[0]; acc[9]  += wv2 * kv[1]; acc[10] += wv2 * kv[2]; acc[11] += wv2 * kv[3];
    acc[12] += wv3 * kv[0]; acc[13] += wv3 * kv[1]; acc[14] += wv3 * kv[2]; acc[15] += wv3 * kv[3];
  }
  size_t gb = ((size_t)bh * NCH + c) * 4096;
  #pragma unroll
  for (int i = 0; i < 4; ++i)
    #pragma unroll
    for (int j = 0; j < 4; ++j)
      G[gb + (size_t)(4 * tv + i) * 64 + 4 * tk + j] = acc[i * 4 + j];
  if (t < 64) {
    float s = 0.f;
    for (int s2 = 0; s2 < 64; ++s2) s += wsh[s2] * Kl[s2][t];
    ng[((size_t)bh * NCH + c) * 64 + t] = s;
  }
}

/* ---------------- state scan: per-element 32-step recurrence (parallel) ---------------- */
__global__ __launch_bounds__(256) void state_scan(const float* __restrict__ G,
                                                  const float* __restrict__ ng,
                                                  const float* __restrict__ decays,
                                                  float* __restrict__ Cst,
                                                  float* __restrict__ nst) {
  int gid = blockIdx.x;
  if (gid < 512) {
    int idx = gid * 256 + threadIdx.x;          /* 131072 C-elements */
    int bh = idx >> 12, e = idx & 4095;
    const float* d = decays + bh * NCH;
    float C = 0.f;
    #pragma unroll
    for (int c = 0; c < NCH; ++c) {
      size_t o = ((size_t)bh * NCH + c) * 4096 + e;
      Cst[o] = C;
      C = d[c] * C + G[o];
    }
  } else {
    int idx = (gid - 512) * 256 + threadIdx.x;  /* 2048 n-elements */
    int bh = idx >> 6, e = idx & 63;
    const float* d = decays + bh * NCH;
    float n = 0.f;
    #pragma unroll
    for (int c = 0; c < NCH; ++c) {
      size_t o = ((size_t)bh * NCH + c) * 64 + e;
      nst[o] = n;
      n = d[c] * n + ng[o];
    }
  }
}

/* ---------------- intra-chunk outputs: fully parallel over (bh,chunk) ---------------- */
__global__ __launch_bounds__(256) void intra(const bf16_t* __restrict__ qb,
                                             const bf16_t* __restrict__ kb,
                                             const bf16_t* __restrict__ vb,
                                             const float* __restrict__ ifb,
                                             const float* __restrict__ blocal,
                                             const float* __restrict__ Mhat,
                                             const float* __restrict__ mstart,
                                             const float* __restrict__ Cst,
                                             const float* __restrict__ nst,
                                             float* __restrict__ ht) {
  int bh = blockIdx.x >> 5, c = blockIdx.x & 31;
  int b = bh >> 3, h = bh & 7;
  __shared__ bf16_t qT[64][68];
  __shared__ bf16_t kT[64][68];
  __shared__ bf16_t vL[64][64];
  __shared__ float  PT[64][65];
  __shared__ float  CT[64][68];
  __shared__ float  nin[64], den[64], ssrc[64], sdst[64], esc[64];
  int t = threadIdx.x;
  size_t tok0 = (size_t)b * Ssz + c * Lc;
  size_t cbase = ((size_t)bh * NCH + c) * 4096;

  for (int idx = t; idx < 4096; idx += 256) {
    int r = idx >> 6, d = idx & 63;
    size_t gi = ((tok0 + r) * Hn + h) * HDsz + d;
    qT[d][r] = qb[gi];
    kT[d][r] = kb[gi];
    vL[r][d] = vb[gi];
    CT[d][r] = Cst[cbase + idx];   /* C[v=r][k=d] -> CT[k][v] */
  }
  if (t < 64) {
    nin[t] = nst[((size_t)bh * NCH + c) * 64 + t];
    float bt = blocal[(size_t)bh * Ssz + c * Lc + t];
    float Mh = Mhat[(size_t)bh * Ssz + c * Lc + t];
    float Mc = mstart[bh * NCH + c];
    float iv = ifb[(tok0 + t) * 16 + h];
    float mt = fmaxf(Mc + bt, Mh);
    ssrc[t] = iv - bt;
    sdst[t] = bt - mt;
    esc[t]  = __expf(Mc + bt - mt);
    den[t]  = 0.f;
  }
  __syncthreads();

  const int tr4 = 4 * (t >> 4), tc4 = 4 * (t & 15);

  /* Step A: raw scores q.k */
  float acc[16];
  #pragma unroll
  for (int i = 0; i < 16; ++i) acc[i] = 0.f;
  for (int d = 0; d < 64; ++d) {
    bf16x4 qv = *(const bf16x4*)&qT[d][tr4];
    bf16x4 kv = *(const bf16x4*)&kT[d][tc4];
    float q0 = (float)qv[0], q1 = (float)qv[1], q2 = (float)qv[2], q3 = (float)qv[3];
    float k0 = (float)kv[0], k1 = (float)kv[1], k2 = (float)kv[2], k3 = (float)kv[3];
    acc[0]  += q0 * k0; acc[1]  += q0 * k1; acc[2]  += q0 * k2; acc[3]  += q0 * k3;
    acc[4]  += q1 * k0; acc[5]  += q1 * k1; acc[6]  += q1 * k2; acc[7]  += q1 * k3;
    acc[8]  += q2 * k0; acc[9]  += q2 * k1; acc[10] += q2 * k2; acc[11] += q2 * k3;
    acc[12] += q3 * k0; acc[13] += q3 * k1; acc[14] += q3 * k2; acc[15] += q3 * k3;
  }
  /* decay-mask weights, write P^T, row-sum partials */
  #pragma unroll
  for (int i = 0; i < 4; ++i) {
    int tau = tr4 + i;
    float sd = sdst[tau];
    float rs = 0.f;
    #pragma unroll
    for (int j = 0; j < 4; ++j) {
      int sg = tc4 + j;
      float p = (sg <= tau) ? acc[i * 4 + j] * __expf(ssrc[sg] + sd) : 0.f;
      PT[sg][tau] = p;
      rs += p;
    }
    atomicAdd(&den[tau], rs);
  }
  __syncthreads();
  if (t < 64) {
    float nq = 0.f;
    for (int k2 = 0; k2 < 64; ++k2) nq += nin[k2] * (float)qT[k2][t];
    float tot = den[t] + esc[t] * nq;
    den[t] = fmaxf(fabsf(tot), 1.0f);
  }
  __syncthreads();

  /* Step B: PV + inter-chunk C_in q */
  float aPV[16], aCq[16];
  #pragma unroll
  for (int i = 0; i < 16; ++i) { aPV[i] = 0.f; aCq[i] = 0.f; }
  for (int s = 0; s < 64; ++s) {
    float p0 = PT[s][tr4], p1 = PT[s][tr4 + 1], p2 = PT[s][tr4 + 2], p3 = PT[s][tr4 + 3];
    bf16x4 vv4 = *(const bf16x4*)&vL[s][tc4];
    float v0 = (float)vv4[0], v1 = (float)vv4[1], v2 = (float)vv4[2], v3 = (float)vv4[3];
    aPV[0]  += p0 * v0; aPV[1]  += p0 * v1; aPV[2]  += p0 * v2; aPV[3]  += p0 * v3;
    aPV[4]  += p1 * v0; aPV[5]  += p1 * v1; aPV[6]  += p1 * v2; aPV[7]  += p1 * v3;
    aPV[8]  += p2 * v0; aPV[9]  += p2 * v1; aPV[10] += p2 * v2; aPV[11] += p2 * v3;
    aPV[12] += p3 * v0; aPV[13] += p3 * v1; aPV[14] += p3 * v2; aPV[15] += p3 * v3;
    bf16x4 qv4 = *(const bf16x4*)&qT[s][tr4];
    f32x4 cv = *(const f32x4*)&CT[s][tc4];
    float q0 = (float)qv4[0], q1 = (float)qv4[1], q2 = (float)qv4[2], q3 = (float)qv4[3];
    aCq[0]  += q0 * cv[0]; aCq[1]  += q0 * cv[1]; aCq[2]  += q0 * cv[2]; aCq[3]  += q0 * cv[3];
    aCq[4]  += q1 * cv[0]; aCq[5]  += q1 * cv[1]; aCq[6]  += q1 * cv[2]; aCq[7]  += q1 * cv[3];
    aCq[8]  += q2 * cv[0]; aCq[9]  += q2 * cv[1]; aCq[10] += q2 * cv[2]; aCq[11] += q2 * cv[3];
    aCq[12] += q3 * cv[0]; aCq[13] += q3 * cv[1]; aCq[14] += q3 * cv[2]; aCq[15] += q3 * cv[3];
  }
  #pragma unroll
  for (int i = 0; i < 4; ++i) {
    int tau = tr4 + i;
    float e = esc[tau], dn = den[tau];
    size_t rowg = ((tok0 + tau) * Hn + h) * HDsz;
    #pragma unroll
    for (int j = 0; j < 4; ++j)
      ht[rowg + tc4 + j] = (aPV[i * 4 + j] + e * aCq[i * 4 + j]) / dn;
  }
}

/* ---------------- group-norm + output gate: gated = sigmoid(og)*GN(ht)*mh_g ---------------- */
__global__ __launch_bounds__(256) void gn_gate(const float* __restrict__ ht,
                                               const bf16_t* __restrict__ og,
                                               const float* __restrict__ mhg,
                                               bf16_t* __restrict__ gated) {
  int gid = blockIdx.x * 4 + (threadIdx.x >> 6);   /* (b*S+s)*8+h */
  int lane = threadIdx.x & 63;
  int h = gid & 7;
  size_t idx = (size_t)gid * 64 + lane;
  float v = ht[idx];
  float s = v;
  #pragma unroll
  for (int o = 1; o < 64; o <<= 1) s += __shfl_xor(s, o, 64);
  float mu = s * (1.f / 64.f);
  float d = v - mu;
  float s2 = d * d;
  #pragma unroll
  for (int o = 1; o < 64; o <<= 1) s2 += __shfl_xor(s2, o, 64);
  float hn = d * rsqrtf(s2 * (1.f / 64.f) + 1e-5f) * mhg[h * 64 + lane];
  gated[idx] = (bf16_t)((float)og[idx] * hn);
}

/* ---------------- launcher ---------------- */
extern "C" void kernel_launch(void* const* d_in, const int* in_sizes, int n_in,
                              void* d_out, int out_size, void* d_ws, size_t ws_size,
                              hipStream_t stream) {
  const float* x     = (const float*)d_in[0];
  const float* ln_g  = (const float*)d_in[1];
  const float* ln_b  = (const float*)d_in[2];
  const float* W_up  = (const float*)d_in[3];
  const float* W_down= (const float*)d_in[4];
  const float* Wq    = (const float*)d_in[5];
  const float* Wk    = (const float*)d_in[6];
  const float* Wv    = (const float*)d_in[7];
  const float* Wi    = (const float*)d_in[8];
  const float* bi    = (const float*)d_in[9];
  const float* Wf    = (const float*)d_in[10];
  const float* bfv   = (const float*)d_in[11];
  const float* Wo    = (const float*)d_in[12];
  const float* bo    = (const float*)d_in[13];
  const float* mh_g  = (const float*)d_in[14];
  const float* W_out = (const float*)d_in[15];

  char* ws = (char*)d_ws;
  bf16_t* hbuf   = (bf16_t*)(ws + OFF_H);
  bf16_t* wupT   = (bf16_t*)(ws + OFF_WUPT);
  bf16_t* wqT    = (bf16_t*)(ws + OFF_WQT);
  bf16_t* wkT    = (bf16_t*)(ws + OFF_WKT);
  bf16_t* wvT    = (bf16_t*)(ws + OFF_WVT);
  bf16_t* woT    = (bf16_t*)(ws + OFF_WOT);
  bf16_t* woutT  = (bf16_t*)(ws + OFF_WOUTT);
  bf16_t* wdownT = (bf16_t*)(ws + OFF_WDOWNT);
  bf16_t* ubuf   = (bf16_t*)(ws + OFF_U);
  bf16_t* qbuf   = (bf16_t*)(ws + OFF_Q);
  bf16_t* kbuf   = (bf16_t*)(ws + OFF_K);
  bf16_t* vbuf   = (bf16_t*)(ws + OFF_V);
  float*  ifb    = (float*)(ws + OFF_IFB);
  float*  bloc   = (float*)(ws + OFF_BLOC);
  float*  Mh     = (float*)(ws + OFF_MHAT);
  float*  mst    = (float*)(ws + OFF_MST);
  float*  Cst    = (float*)(ws + OFF_CST);
  float*  nst    = (float*)(ws + OFF_NST);
  float*  htbuf  = (float*)(ws + OFF_HT);
  float*  Ginc   = (float*)(ws + OFF_GINC);
  float*  ngbuf  = (float*)(ws + OFF_NG);
  float*  decays = (float*)(ws + OFF_DEC);
  float*  mendb  = (float*)(ws + OFF_MEND);
  bf16_t* ogbuf  = (bf16_t*)(ws + OFF_OG);
  bf16_t* gbuf   = (bf16_t*)(ws + OFF_G);
  bf16_t* ybuf   = (bf16_t*)(ws + OFF_Y);

  dim3 tb(32, 8);
  transpose_cast<<<dim3(Isz / 32, Dsz / 32), tb, 0, stream>>>(W_up, wupT, Dsz, Isz);
  transpose_cast<<<dim3(512 / 32, Isz / 32), tb, 0, stream>>>(Wq, wqT, Isz, 512);
  transpose_cast<<<dim3(512 / 32, Isz / 32), tb, 0, stream>>>(Wk, wkT, Isz, 512);
  transpose_cast<<<dim3(512 / 32, Isz / 32), tb, 0, stream>>>(Wv, wvT, Isz, 512);
  transpose_cast<<<dim3(512 / 32, Isz / 32), tb, 0, stream>>>(Wo, woT, Isz, 512);
  transpose_cast<<<dim3(Isz / 32, 512 / 32), tb, 0, stream>>>(W_out, woutT, 512, Isz);
  transpose_cast<<<dim3(Dsz / 32, Isz / 32), tb, 0, stream>>>(W_down, wdownT, Isz, Dsz);

  ln_kernel<<<NTOK, 256, 0, stream>>>(x, ln_g, ln_b, hbuf);

  gemm_bt<0><<<dim3(Isz / 128, NTOK / 128), 256, 0, stream>>>(hbuf, wupT, ubuf, nullptr, NTOK, Isz, Dsz, 1.f);
  gemm_bt<0><<<dim3(512 / 128, NTOK / 128), 256, 0, stream>>>(ubuf, wqT, qbuf, nullptr, NTOK, 512, Isz, 1.f);
  gemm_bt<1><<<dim3(512 / 128, NTOK / 128), 256, 0, stream>>>(ubuf, wkT, kbuf, nullptr, NTOK, 512, Isz, 0.125f);
  gemm_bt<0><<<dim3(512 / 128, NTOK / 128), 256, 0, stream>>>(ubuf, wvT, vbuf, nullptr, NTOK, 512, Isz, 1.f);

  ifproj<<<NTOK, 256, 0, stream>>>(ubuf, Wi, bi, Wf, bfv, ifb);
  gates_a<<<NBH * NCH, 64, 0, stream>>>(ifb, bloc, Mh);
  gates_b<<<1, 32, 0, stream>>>(bloc, Mh, mst, decays, mendb);
  chunk_inc<<<NBH * NCH, 256, 0, stream>>>(kbuf, vbuf, ifb, bloc, mendb, Ginc, ngbuf);
  state_scan<<<520, 256, 0, stream>>>(Ginc, ngbuf, decays, Cst, nst);
  intra<<<NBH * NCH, 256, 0, stream>>>(qbuf, kbuf, vbuf, ifb, bloc, Mh, mst, Cst, nst, htbuf);

  gemm_bt<2><<<dim3(512 / 128, NTOK / 128), 256, 0, stream>>>(ubuf, woT, ogbuf, bo, NTOK, 512, Isz, 1.f);
  gn_gate<<<NTOK * Hn / 4, 256, 0, stream>>>(htbuf, ogbuf, mh_g, gbuf);
  gemm_bt<0><<<dim3(Isz / 128, NTOK / 128), 256, 0, stream>>>(gbuf, woutT, ybuf, nullptr, NTOK, Isz, 512, 1.f);
  gemm_bt<3><<<dim3(Dsz / 128, NTOK / 128), 256, 0, stream>>>(ybuf, wdownT, (float*)d_out, x, NTOK, Dsz, Isz, 1.f);
}

// Round 3
// 313.148 us; speedup vs baseline: 1.7967x; 1.3052x over previous
//
#include <hip/hip_runtime.h>
#include <hip/hip_bf16.h>
#include <stdint.h>
#include <stddef.h>

typedef __bf16 bf16_t;
typedef __bf16 bf16x4 __attribute__((ext_vector_type(4)));
typedef __bf16 bf16x8 __attribute__((ext_vector_type(8)));
typedef float  f32x4  __attribute__((ext_vector_type(4)));

#define Bsz  4
#define Ssz  2048
#define Dsz  768
#define Isz  1536
#define Hn   8
#define HDsz 64
#define NTOK (Bsz*Ssz)      /* 8192 */
#define Lc   64
#define NCH  (Ssz/Lc)       /* 32 */
#define NBH  (Bsz*Hn)       /* 32 */

/* ---------------- workspace layout (bytes) ---------------- */
#define OFF_H      ((size_t)0)                    /* ln out bf16 12.58M; CstB aliases after up-gemm */
#define OFF_WUPT   ((size_t)12582912)
#define OFF_WQKVO  ((size_t)14942208)             /* 2048x1536 bf16 */
#define OFF_WOUTT  ((size_t)21233664)
#define OFF_WDOWNT ((size_t)22806528)
#define OFF_U      ((size_t)25165824)             /* 25.17M; HT/G/gated alias after u dead */
#define OFF_QKVO   ((size_t)50331648)             /* 8192x2048 bf16; y aliases */
#define OFF_KT     ((size_t)83886080)             /* [bh][64][2048] bf16 */
#define OFF_VT     ((size_t)92274688)
#define OFF_IFB    ((size_t)100663296)
#define OFF_BLOC   ((size_t)101187584)
#define OFF_MHAT   ((size_t)101449728)
#define OFF_MST    ((size_t)101711872)
#define OFF_DEC    ((size_t)101715968)
#define OFF_MEND   ((size_t)101720064)
#define OFF_NG     ((size_t)101724160)
#define OFF_NST    ((size_t)101986304)
#define OFF_WIFT   ((size_t)102248448)            /* 16x1536 bf16 */
/* aliases */
#define OFF_CSTB   ((size_t)0)                    /* 32*32*4096 bf16 = 8.39M (over H) */
#define OFF_HT     OFF_U                          /* 8192*512 f32 = 16.78M */
#define OFF_G      OFF_U                          /* 32*32*4096 bf16 = 8.39M (scan input, dead before ht write) */
#define OFF_GATED  (OFF_U + 16777216)             /* 8192*512 bf16 = 8.39M */
#define OFF_Y      OFF_QKVO                       /* 8192*1536 bf16 */

/* ---------------- helpers ---------------- */
__device__ __forceinline__ void gload16(const void* gsrc, void* ldst) {
  __builtin_amdgcn_global_load_lds(
      (const __attribute__((address_space(1))) void*)gsrc,
      (__attribute__((address_space(3))) void*)ldst, 16, 0, 0);
}

__device__ __forceinline__ float blockReduceSum256(float v) {
  #pragma unroll
  for (int o = 1; o < 64; o <<= 1) v += __shfl_xor(v, o, 64);
  __shared__ float sh[4];
  int wid = threadIdx.x >> 6;
  __syncthreads();
  if ((threadIdx.x & 63) == 0) sh[wid] = v;
  __syncthreads();
  return sh[0] + sh[1] + sh[2] + sh[3];
}

/* ---------------- weight transpose+cast: W (K,N) f32 -> Wt (N,K) bf16, *scale ---------------- */
__global__ __launch_bounds__(256) void transpose_cast(const float* __restrict__ W,
                                                      bf16_t* __restrict__ Wt,
                                                      int K, int N, float scale) {
  __shared__ float tile[32][33];
  int n0 = blockIdx.x * 32, k0 = blockIdx.y * 32;
  int tx = threadIdx.x, ty = threadIdx.y;   /* block (32,8) */
  #pragma unroll
  for (int j = 0; j < 32; j += 8)
    tile[ty + j][tx] = W[(size_t)(k0 + ty + j) * N + n0 + tx];
  __syncthreads();
  #pragma unroll
  for (int j = 0; j < 32; j += 8)
    Wt[(size_t)(n0 + ty + j) * K + k0 + tx] = (bf16_t)(tile[tx][ty + j] * scale);
}

/* ---------------- build WifT: [16][1536] bf16 (rows 0-7 Wi^T, 8-15 Wf^T) ---------------- */
__global__ __launch_bounds__(256) void build_wift(const float* __restrict__ Wi,
                                                  const float* __restrict__ Wf,
                                                  bf16_t* __restrict__ WifT) {
  int idx = blockIdx.x * 256 + threadIdx.x;   /* 96 blocks */
  if (idx < 16 * 1536) {
    int n = idx / 1536, k = idx - n * 1536;
    float v = (n < 8) ? Wi[(size_t)k * 8 + n] : Wf[(size_t)k * 8 + (n - 8)];
    WifT[idx] = (bf16_t)v;
  }
}

/* ---------------- LayerNorm: x f32 (tok,768) -> h bf16 ---------------- */
__global__ __launch_bounds__(256) void ln_kernel(const float* __restrict__ x,
                                                 const float* __restrict__ g,
                                                 const float* __restrict__ bta,
                                                 bf16_t* __restrict__ h) {
  size_t tok = blockIdx.x;
  const float* xr = x + tok * Dsz;
  int t = threadIdx.x;
  float v[3]; float s = 0.f;
  #pragma unroll
  for (int i = 0; i < 3; ++i) { v[i] = xr[t + 256 * i]; s += v[i]; }
  s = blockReduceSum256(s);
  float mu = s * (1.f / Dsz);
  float s2 = 0.f;
  #pragma unroll
  for (int i = 0; i < 3; ++i) { float d = v[i] - mu; s2 += d * d; }
  s2 = blockReduceSum256(s2);
  float rs = rsqrtf(s2 * (1.f / Dsz) + 1e-5f);
  #pragma unroll
  for (int i = 0; i < 3; ++i) {
    int col = t + 256 * i;
    h[tok * Dsz + col] = (bf16_t)((v[i] - mu) * rs * g[col] + bta[col]);
  }
}

/* ---------------- bf16 MFMA GEMM: C(M,N) = A(M,K) @ Bt(N,K)^T  ---------------- */
/* EPI: 0 = bf16 out; 3 = f32 out = acc + resid[row*N+col];
        4 = qkvo: col<1536 plain bf16, col>=1536 sigmoid(acc + bo[col-1536]) */
template<int EPI>
__global__ __launch_bounds__(256) void gemm_bt(const bf16_t* __restrict__ A,
                                               const bf16_t* __restrict__ Bt,
                                               void* __restrict__ Cout,
                                               const void* __restrict__ extra,
                                               int M, int N, int K) {
  __shared__ bf16_t As[128 * 64];
  __shared__ bf16_t Bs[128 * 64];
  const int t = threadIdx.x;
  const int w = t >> 6, l = t & 63;
  const int tile_m = blockIdx.y * 128, tile_n = blockIdx.x * 128;
  const int wr = w >> 1, wc = w & 1;
  const int lrow = l >> 3, lk = (l & 7) * 8;
  const int l15 = l & 15, l4 = l >> 4;

  f32x4 acc[4][4];
  #pragma unroll
  for (int m = 0; m < 4; ++m)
    #pragma unroll
    for (int n = 0; n < 4; ++n) acc[m][n] = (f32x4){0.f, 0.f, 0.f, 0.f};

  for (int k0 = 0; k0 < K; k0 += 64) {
    #pragma unroll
    for (int i = 0; i < 4; ++i) {
      int ch = w * 4 + i;
      int row = ch * 8 + lrow;
      const bf16_t* ga = A  + (size_t)(tile_m + row) * K + k0 + lk;
      const bf16_t* gb = Bt + (size_t)(tile_n + row) * K + k0 + lk;
      gload16(ga, &As[ch * 512]);
      gload16(gb, &Bs[ch * 512]);
    }
    __syncthreads();
    #pragma unroll
    for (int kk = 0; kk < 2; ++kk) {
      bf16x8 af[4], bfr[4];
      #pragma unroll
      for (int m = 0; m < 4; ++m)
        af[m] = *(const bf16x8*)&As[(wr * 64 + m * 16 + l15) * 64 + kk * 32 + l4 * 8];
      #pragma unroll
      for (int n = 0; n < 4; ++n)
        bfr[n] = *(const bf16x8*)&Bs[(wc * 64 + n * 16 + l15) * 64 + kk * 32 + l4 * 8];
      #pragma unroll
      for (int m = 0; m < 4; ++m)
        #pragma unroll
        for (int n = 0; n < 4; ++n)
          acc[m][n] = __builtin_amdgcn_mfma_f32_16x16x32_bf16(af[m], bfr[n], acc[m][n], 0, 0, 0);
    }
    __syncthreads();
  }

  const int rbase = tile_m + wr * 64 + l4 * 4;
  const int cbase = tile_n + wc * 64 + l15;
  #pragma unroll
  for (int m = 0; m < 4; ++m)
    #pragma unroll
    for (int n = 0; n < 4; ++n)
      #pragma unroll
      for (int j = 0; j < 4; ++j) {
        int row = rbase + m * 16 + j;
        int col = cbase + n * 16;
        float v = acc[m][n][j];
        if constexpr (EPI == 0) {
          ((bf16_t*)Cout)[(size_t)row * N + col] = (bf16_t)v;
        } else if constexpr (EPI == 3) {
          ((float*)Cout)[(size_t)row * N + col] =
              v + ((const float*)extra)[(size_t)row * N + col];
        } else {  /* EPI == 4 */
          if (col < 1536) {
            ((bf16_t*)Cout)[(size_t)row * N + col] = (bf16_t)v;
          } else {
            float z = v + ((const float*)extra)[col - 1536];
            ((bf16_t*)Cout)[(size_t)row * N + col] = (bf16_t)(1.f / (1.f + __expf(-z)));
          }
        }
      }
}

/* ---------------- i/f gate projection as tiny MFMA GEMM: M=8192 N=16 K=1536 ---------------- */
__global__ __launch_bounds__(256) void ifproj_mfma(const bf16_t* __restrict__ u,
                                                   const bf16_t* __restrict__ WifT,
                                                   const float* __restrict__ bi,
                                                   const float* __restrict__ bfv,
                                                   float* __restrict__ ifb) {
  __shared__ bf16_t As[128 * 64];
  __shared__ bf16_t Bs[16 * 64];
  const int t = threadIdx.x, w = t >> 6, l = t & 63;
  const int l15 = l & 15, l4 = l >> 4;
  const int lrow = l >> 3, lk = (l & 7) * 8;
  const int tile_m = blockIdx.x * 128;
  f32x4 acc[2];
  acc[0] = (f32x4){0.f, 0.f, 0.f, 0.f};
  acc[1] = (f32x4){0.f, 0.f, 0.f, 0.f};

  for (int k0 = 0; k0 < Isz; k0 += 64) {
    #pragma unroll
    for (int i = 0; i < 4; ++i) {
      int ch = w * 4 + i;
      int row = ch * 8 + lrow;
      gload16(u + (size_t)(tile_m + row) * Isz + k0 + lk, &As[ch * 512]);
    }
    if (t < 128) {
      int rr = t >> 3, c0 = (t & 7) * 8;
      *(bf16x8*)&Bs[rr * 64 + c0] = *(const bf16x8*)(WifT + (size_t)rr * Isz + k0 + c0);
    }
    __syncthreads();
    #pragma unroll
    for (int kk = 0; kk < 2; ++kk) {
      bf16x8 bfr = *(const bf16x8*)&Bs[l15 * 64 + kk * 32 + l4 * 8];
      #pragma unroll
      for (int m = 0; m < 2; ++m) {
        bf16x8 af = *(const bf16x8*)&As[(w * 32 + m * 16 + l15) * 64 + kk * 32 + l4 * 8];
        acc[m] = __builtin_amdgcn_mfma_f32_16x16x32_bf16(af, bfr, acc[m], 0, 0, 0);
      }
    }
    __syncthreads();
  }
  float bias = (l15 < 8) ? bi[l15] : bfv[l15 - 8];
  #pragma unroll
  for (int m = 0; m < 2; ++m)
    #pragma unroll
    for (int j = 0; j < 4; ++j) {
      int row = tile_m + w * 32 + m * 16 + l4 * 4 + j;
      ifb[(size_t)row * 16 + l15] = acc[m][j] + bias;
    }
}

/* ---------------- gates pass A: per (bh,chunk) local cumsum + prefix-max ---------------- */
__global__ __launch_bounds__(64) void gates_a(const float* __restrict__ ifb,
                                              float* __restrict__ blocal,
                                              float* __restrict__ Mhat) {
  int bh = blockIdx.x >> 5, c = blockIdx.x & 31;
  int b = bh >> 3, h = bh & 7;
  int lane = threadIdx.x;
  size_t tok = (size_t)b * Ssz + c * Lc + lane;
  float iv = ifb[tok * 16 + h];
  float fv = ifb[tok * 16 + 8 + h];
  float bt = fv;
  #pragma unroll
  for (int d = 1; d < 64; d <<= 1) { float o = __shfl_up(bt, d, 64); if (lane >= d) bt += o; }
  float a = iv - bt;
  float pm = a;
  #pragma unroll
  for (int d = 1; d < 64; d <<= 1) { float o = __shfl_up(pm, d, 64); if (lane >= d) pm = fmaxf(pm, o); }
  blocal[(size_t)bh * Ssz + c * Lc + lane] = bt;
  Mhat[(size_t)bh * Ssz + c * Lc + lane] = bt + pm;
}

/* ---------------- gates pass B: sequential chunk-boundary m recurrence + decays ---------------- */
__global__ void gates_b(const float* __restrict__ blocal, const float* __restrict__ Mhat,
                        float* __restrict__ mstart, float* __restrict__ decays,
                        float* __restrict__ mend) {
  int bh = threadIdx.x;
  if (bh < NBH) {
    float M = 0.f;
    for (int c = 0; c < NCH; ++c) {
      mstart[bh * NCH + c] = M;
      float bL = blocal[(size_t)bh * Ssz + c * Lc + 63];
      float Mh = Mhat[(size_t)bh * Ssz + c * Lc + 63];
      float Mn = fmaxf(M + bL, Mh);
      decays[bh * NCH + c] = __expf(M + bL - Mn);
      mend[bh * NCH + c] = Mn;
      M = Mn;
    }
  }
}

/* ---------------- k/v transpose: qkvo cols -> kT/vT [bh][64 d][2048 s] bf16 ---------------- */
__global__ __launch_bounds__(256) void kv_transpose(const bf16_t* __restrict__ qkvo,
                                                    bf16_t* __restrict__ kTg,
                                                    bf16_t* __restrict__ vTg) {
  int bh = blockIdx.x >> 5, st = blockIdx.x & 31;
  int b = bh >> 3, h = bh & 7;
  __shared__ bf16_t Lk[64 * 72];
  __shared__ bf16_t Lv[64 * 72];
  int t = threadIdx.x;
  size_t tok0 = (size_t)b * Ssz + st * 64;
  #pragma unroll
  for (int i = 0; i < 2; ++i) {
    int e = t + i * 256; int r = e >> 3, c0 = (e & 7) * 8;
    bf16x8 kv = *(const bf16x8*)(qkvo + (tok0 + r) * 2048 + 512 + h * 64 + c0);
    bf16x8 vv = *(const bf16x8*)(qkvo + (tok0 + r) * 2048 + 1024 + h * 64 + c0);
    *(bf16x8*)&Lk[r * 72 + c0] = kv;
    *(bf16x8*)&Lv[r * 72 + c0] = vv;
  }
  __syncthreads();
  #pragma unroll
  for (int i = 0; i < 2; ++i) {
    int e = t + i * 256; int d = e >> 3, s0 = (e & 7) * 8;
    bf16x8 ok, ov;
    #pragma unroll
    for (int j = 0; j < 8; ++j) {
      ok[j] = Lk[(s0 + j) * 72 + d];
      ov[j] = Lv[(s0 + j) * 72 + d];
    }
    *(bf16x8*)(kTg + ((size_t)bh * 64 + d) * Ssz + st * 64 + s0) = ok;
    *(bf16x8*)(vTg + ((size_t)bh * 64 + d) * Ssz + st * 64 + s0) = ov;
  }
}

/* ---------------- per-chunk state increment, MFMA: G[v][k] = sum_s w_s V[s][v] K[s][k] ---------------- */
__global__ __launch_bounds__(256) void chunk_inc_mfma(const bf16_t* __restrict__ kTg,
                                                      const bf16_t* __restrict__ vTg,
                                                      const float* __restrict__ ifb,
                                                      const float* __restrict__ blocal,
                                                      const float* __restrict__ mend,
                                                      bf16_t* __restrict__ G,
                                                      float* __restrict__ ng) {
  int bh = blockIdx.x >> 5, c = blockIdx.x & 31;
  int b = bh >> 3, h = bh & 7;
  __shared__ bf16_t Vt[64 * 64];   /* [v][s] */
  __shared__ bf16_t Kw[64 * 64];   /* [k][s] pre-weighted by w_s */
  __shared__ float wsh[64];
  const int t = threadIdx.x, w = t >> 6, l = t & 63;
  const int l15 = l & 15, l4 = l >> 4;
  if (t < 64) {
    float mL = mend[bh * NCH + c];
    float bL = blocal[(size_t)bh * Ssz + c * Lc + 63];
    float bt = blocal[(size_t)bh * Ssz + c * Lc + t];
    float iv = ifb[((size_t)b * Ssz + c * Lc + t) * 16 + h];
    wsh[t] = __expf(iv + bL - bt - mL);
  }
  __syncthreads();
  {
    const int r = l >> 3, c8 = (l & 7) * 8;
    #pragma unroll
    for (int i = 0; i < 2; ++i) {
      int seg = w * 2 + i, row = seg * 8 + r;
      gload16(vTg + ((size_t)bh * 64 + row) * Ssz + c * 64 + c8, &Vt[seg * 512]);
    }
    #pragma unroll
    for (int i = 0; i < 2; ++i) {
      int e = t + i * 256; int row = e >> 3, c0 = (e & 7) * 8;
      bf16x8 kv = *(const bf16x8*)(kTg + ((size_t)bh * 64 + row) * Ssz + c * 64 + c0);
      #pragma unroll
      for (int j = 0; j < 8; ++j) kv[j] = (bf16_t)((float)kv[j] * wsh[c0 + j]);
      *(bf16x8*)&Kw[row * 64 + c0] = kv;
    }
  }
  __syncthreads();
  f32x4 acc[4];
  #pragma unroll
  for (int n = 0; n < 4; ++n) acc[n] = (f32x4){0.f, 0.f, 0.f, 0.f};
  #pragma unroll
  for (int kk = 0; kk < 2; ++kk) {
    bf16x8 af = *(const bf16x8*)&Vt[(w * 16 + l15) * 64 + kk * 32 + l4 * 8];
    #pragma unroll
    for (int n = 0; n < 4; ++n) {
      bf16x8 bfr = *(const bf16x8*)&Kw[(n * 16 + l15) * 64 + kk * 32 + l4 * 8];
      acc[n] = __builtin_amdgcn_mfma_f32_16x16x32_bf16(af, bfr, acc[n], 0, 0, 0);
    }
  }
  size_t gb = ((size_t)bh * NCH + c) * 4096;
  #pragma unroll
  for (int n = 0; n < 4; ++n)
    #pragma unroll
    for (int j = 0; j < 4; ++j) {
      int row = w * 16 + l4 * 4 + j;       /* v */
      int col = n * 16 + l15;              /* k */
      G[gb + (size_t)row * 64 + col] = (bf16_t)acc[n][j];
    }
  if (t < 64) {
    float s = 0.f;
    for (int s2 = 0; s2 < 64; ++s2) s += (float)Kw[t * 64 + s2];
    ng[((size_t)bh * NCH + c) * 64 + t] = s;
  }
}

/* ---------------- state scan: per-element 32-step recurrence (parallel) ---------------- */
__global__ __launch_bounds__(256) void state_scan(const bf16_t* __restrict__ G,
                                                  const float* __restrict__ ng,
                                                  const float* __restrict__ decays,
                                                  bf16_t* __restrict__ CstB,
                                                  float* __restrict__ nst) {
  int gid = blockIdx.x;
  if (gid < 512) {
    int idx = gid * 256 + threadIdx.x;
    int bh = idx >> 12, e = idx & 4095;
    const float* d = decays + bh * NCH;
    float C = 0.f;
    #pragma unroll
    for (int c = 0; c < NCH; ++c) {
      size_t o = ((size_t)bh * NCH + c) * 4096 + e;
      CstB[o] = (bf16_t)C;
      C = d[c] * C + (float)G[o];
    }
  } else {
    int idx = (gid - 512) * 256 + threadIdx.x;
    int bh = idx >> 6, e = idx & 63;
    const float* d = decays + bh * NCH;
    float n = 0.f;
    #pragma unroll
    for (int c = 0; c < NCH; ++c) {
      size_t o = ((size_t)bh * NCH + c) * 64 + e;
      nst[o] = n;
      n = d[c] * n + ng[o];
    }
  }
}

/* ---------------- intra-chunk outputs, MFMA ---------------- */
__global__ __launch_bounds__(256) void intra_mfma(const bf16_t* __restrict__ qkvo,
                                                  const bf16_t* __restrict__ vTg,
                                                  const bf16_t* __restrict__ CstB,
                                                  const float* __restrict__ nst,
                                                  const float* __restrict__ ifb,
                                                  const float* __restrict__ blocal,
                                                  const float* __restrict__ Mhat,
                                                  const float* __restrict__ mstart,
                                                  float* __restrict__ ht) {
  int bh = blockIdx.x >> 5, c = blockIdx.x & 31;
  int b = bh >> 3, h = bh & 7;
  __shared__ bf16_t qs[64 * 64];    /* q rows (later esc-scaled) */
  __shared__ bf16_t ks[64 * 64];    /* k rows; aliased as P after QK^T */
  __shared__ bf16_t vTs[64 * 64];   /* V^T [d][s] */
  __shared__ bf16_t Cs[64 * 64];    /* C [v][k] bf16 */
  __shared__ float nin[64], den_s[64], ssrc[64], sdst[64], esc[64];
  const int t = threadIdx.x, w = t >> 6, l = t & 63;
  const int l15 = l & 15, l4 = l >> 4;
  const size_t tok0 = (size_t)b * Ssz + c * Lc;
  const size_t cbase = ((size_t)bh * NCH + c) * 4096;

  if (t < 64) {
    nin[t] = nst[((size_t)bh * NCH + c) * 64 + t];
    float bt = blocal[(size_t)bh * Ssz + c * Lc + t];
    float Mh2 = Mhat[(size_t)bh * Ssz + c * Lc + t];
    float Mc = mstart[bh * NCH + c];
    float iv = ifb[(tok0 + t) * 16 + h];
    float mt = fmaxf(Mc + bt, Mh2);
    ssrc[t] = iv - bt;
    sdst[t] = bt - mt;
    esc[t]  = __expf(Mc + bt - mt);
  }
  {
    const int r = l >> 3, c8 = (l & 7) * 8;
    #pragma unroll
    for (int i = 0; i < 2; ++i) {
      int seg = w * 2 + i, row = seg * 8 + r;
      gload16(qkvo + (tok0 + row) * 2048 + h * 64 + c8,          &qs[seg * 512]);
      gload16(qkvo + (tok0 + row) * 2048 + 512 + h * 64 + c8,    &ks[seg * 512]);
      gload16(vTg + ((size_t)bh * 64 + row) * Ssz + c * 64 + c8, &vTs[seg * 512]);
      gload16(CstB + cbase + seg * 512 + l * 8,                  &Cs[seg * 512]);
    }
  }
  __syncthreads();

  /* QK^T: wave w owns output rows tau in [w*16, w*16+16) */
  f32x4 aS[4];
  #pragma unroll
  for (int n = 0; n < 4; ++n) aS[n] = (f32x4){0.f, 0.f, 0.f, 0.f};
  #pragma unroll
  for (int kk = 0; kk < 2; ++kk) {
    bf16x8 af = *(const bf16x8*)&qs[(w * 16 + l15) * 64 + kk * 32 + l4 * 8];
    #pragma unroll
    for (int n = 0; n < 4; ++n) {
      bf16x8 bfr = *(const bf16x8*)&ks[(n * 16 + l15) * 64 + kk * 32 + l4 * 8];
      aS[n] = __builtin_amdgcn_mfma_f32_16x16x32_bf16(af, bfr, aS[n], 0, 0, 0);
    }
  }
  /* scale own q rows by esc (feeds Cq MFMA and nq, both esc-weighted) */
  {
    int row = w * 16 + (l >> 2);
    int c0 = (l & 3) * 16;
    float e = esc[row];
    #pragma unroll
    for (int i2 = 0; i2 < 2; ++i2) {
      bf16x8 v8 = *(const bf16x8*)&qs[row * 64 + c0 + i2 * 8];
      #pragma unroll
      for (int j = 0; j < 8; ++j) v8[j] = (bf16_t)((float)v8[j] * e);
      *(bf16x8*)&qs[row * 64 + c0 + i2 * 8] = v8;
    }
  }
  /* decay mask + exp, row-sum partials */
  float rs[4] = {0.f, 0.f, 0.f, 0.f};
  #pragma unroll
  for (int n = 0; n < 4; ++n) {
    int col = n * 16 + l15;
    float es = ssrc[col];
    #pragma unroll
    for (int j = 0; j < 4; ++j) {
      int row = w * 16 + l4 * 4 + j;
      float p = (col <= row) ? aS[n][j] * __expf(es + sdst[row]) : 0.f;
      aS[n][j] = p;
      rs[j] += p;
    }
  }
  #pragma unroll
  for (int j = 0; j < 4; ++j) {
    rs[j] += __shfl_xor(rs[j], 1, 64);
    rs[j] += __shfl_xor(rs[j], 2, 64);
    rs[j] += __shfl_xor(rs[j], 4, 64);
    rs[j] += __shfl_xor(rs[j], 8, 64);
  }
  if (l15 == 0) {
    #pragma unroll
    for (int j = 0; j < 4; ++j) den_s[w * 16 + l4 * 4 + j] = rs[j];
  }
  __syncthreads();   /* all ks B-reads done; den row-sums visible */

  /* store P (bf16) over ks */
  #pragma unroll
  for (int n = 0; n < 4; ++n)
    #pragma unroll
    for (int j = 0; j < 4; ++j)
      ks[(w * 16 + l4 * 4 + j) * 64 + n * 16 + l15] = (bf16_t)aS[n][j];

  /* den finalize: add esc*n.q (qs already esc-scaled) */
  {
    int row = w * 16 + (l >> 2);
    int c0 = (l & 3) * 16;
    float part = 0.f;
    #pragma unroll
    for (int i2 = 0; i2 < 16; ++i2)
      part += (float)qs[row * 64 + c0 + i2] * nin[c0 + i2];
    part += __shfl_xor(part, 1, 64);
    part += __shfl_xor(part, 2, 64);
    if ((l & 3) == 0)
      den_s[row] = fmaxf(fabsf(den_s[row] + part), 1.0f);
  }
  __syncthreads();   /* P + den complete */

  /* out = P.V + q_esc.C, one accumulator */
  f32x4 aO[4];
  #pragma unroll
  for (int n = 0; n < 4; ++n) aO[n] = (f32x4){0.f, 0.f, 0.f, 0.f};
  #pragma unroll
  for (int kk = 0; kk < 2; ++kk) {
    bf16x8 afP = *(const bf16x8*)&ks[(w * 16 + l15) * 64 + kk * 32 + l4 * 8];
    bf16x8 afQ = *(const bf16x8*)&qs[(w * 16 + l15) * 64 + kk * 32 + l4 * 8];
    #pragma unroll
    for (int n = 0; n < 4; ++n) {
      bf16x8 bV = *(const bf16x8*)&vTs[(n * 16 + l15) * 64 + kk * 32 + l4 * 8];
      bf16x8 bC = *(const bf16x8*)&Cs[(n * 16 + l15) * 64 + kk * 32 + l4 * 8];
      aO[n] = __builtin_amdgcn_mfma_f32_16x16x32_bf16(afP, bV, aO[n], 0, 0, 0);
      aO[n] = __builtin_amdgcn_mfma_f32_16x16x32_bf16(afQ, bC, aO[n], 0, 0, 0);
    }
  }
  #pragma unroll
  for (int j = 0; j < 4; ++j) {
    int row = w * 16 + l4 * 4 + j;
    float rinv = 1.f / den_s[row];
    size_t rowg = ((tok0 + row) * Hn + h) * HDsz;
    #pragma unroll
    for (int n = 0; n < 4; ++n)
      ht[rowg + n * 16 + l15] = aO[n][j] * rinv;
  }
}

/* ---------------- group-norm + output gate: gated = sigmoid(og)*GN(ht)*mh_g ---------------- */
__global__ __launch_bounds__(256) void gn_gate(const float* __restrict__ ht,
                                               const bf16_t* __restrict__ qkvo,
                                               const float* __restrict__ mhg,
                                               bf16_t* __restrict__ gated) {
  int gid = blockIdx.x * 4 + (threadIdx.x >> 6);   /* (b*S+s)*8+h */
  int lane = threadIdx.x & 63;
  int h = gid & 7;
  size_t tok = (size_t)(gid >> 3);
  size_t idx = (size_t)gid * 64 + lane;
  float v = ht[idx];
  float s = v;
  #pragma unroll
  for (int o = 1; o < 64; o <<= 1) s += __shfl_xor(s, o, 64);
  float mu = s * (1.f / 64.f);
  float d = v - mu;
  float s2 = d * d;
  #pragma unroll
  for (int o = 1; o < 64; o <<= 1) s2 += __shfl_xor(s2, o, 64);
  float hn = d * rsqrtf(s2 * (1.f / 64.f) + 1e-5f) * mhg[h * 64 + lane];
  float og = (float)qkvo[tok * 2048 + 1536 + h * 64 + lane];
  gated[idx] = (bf16_t)(og * hn);
}

/* ---------------- launcher ---------------- */
extern "C" void kernel_launch(void* const* d_in, const int* in_sizes, int n_in,
                              void* d_out, int out_size, void* d_ws, size_t ws_size,
                              hipStream_t stream) {
  const float* x     = (const float*)d_in[0];
  const float* ln_g  = (const float*)d_in[1];
  const float* ln_b  = (const float*)d_in[2];
  const float* W_up  = (const float*)d_in[3];
  const float* W_down= (const float*)d_in[4];
  const float* Wq    = (const float*)d_in[5];
  const float* Wk    = (const float*)d_in[6];
  const float* Wv    = (const float*)d_in[7];
  const float* Wi    = (const float*)d_in[8];
  const float* bi    = (const float*)d_in[9];
  const float* Wf    = (const float*)d_in[10];
  const float* bfv   = (const float*)d_in[11];
  const float* Wo    = (const float*)d_in[12];
  const float* bo    = (const float*)d_in[13];
  const float* mh_g  = (const float*)d_in[14];
  const float* W_out = (const float*)d_in[15];

  char* ws = (char*)d_ws;
  bf16_t* hbuf   = (bf16_t*)(ws + OFF_H);
  bf16_t* wupT   = (bf16_t*)(ws + OFF_WUPT);
  bf16_t* wqkvoT = (bf16_t*)(ws + OFF_WQKVO);
  bf16_t* woutT  = (bf16_t*)(ws + OFF_WOUTT);
  bf16_t* wdownT = (bf16_t*)(ws + OFF_WDOWNT);
  bf16_t* ubuf   = (bf16_t*)(ws + OFF_U);
  bf16_t* qkvob  = (bf16_t*)(ws + OFF_QKVO);
  bf16_t* kTg    = (bf16_t*)(ws + OFF_KT);
  bf16_t* vTg    = (bf16_t*)(ws + OFF_VT);
  float*  ifb    = (float*)(ws + OFF_IFB);
  float*  bloc   = (float*)(ws + OFF_BLOC);
  float*  Mh     = (float*)(ws + OFF_MHAT);
  float*  mst    = (float*)(ws + OFF_MST);
  float*  decays = (float*)(ws + OFF_DEC);
  float*  mendb  = (float*)(ws + OFF_MEND);
  float*  ngbuf  = (float*)(ws + OFF_NG);
  float*  nst    = (float*)(ws + OFF_NST);
  bf16_t* wifT   = (bf16_t*)(ws + OFF_WIFT);
  bf16_t* CstB   = (bf16_t*)(ws + OFF_CSTB);
  float*  htbuf  = (float*)(ws + OFF_HT);
  bf16_t* Gbuf   = (bf16_t*)(ws + OFF_G);
  bf16_t* gbuf   = (bf16_t*)(ws + OFF_GATED);
  bf16_t* ybuf   = (bf16_t*)(ws + OFF_Y);

  dim3 tb(32, 8);
  transpose_cast<<<dim3(Isz / 32, Dsz / 32), tb, 0, stream>>>(W_up, wupT, Dsz, Isz, 1.f);
  transpose_cast<<<dim3(512 / 32, Isz / 32), tb, 0, stream>>>(Wq, wqkvoT,                    Isz, 512, 1.f);
  transpose_cast<<<dim3(512 / 32, Isz / 32), tb, 0, stream>>>(Wk, wqkvoT + (size_t)512*Isz,  Isz, 512, 0.125f);
  transpose_cast<<<dim3(512 / 32, Isz / 32), tb, 0, stream>>>(Wv, wqkvoT + (size_t)1024*Isz, Isz, 512, 1.f);
  transpose_cast<<<dim3(512 / 32, Isz / 32), tb, 0, stream>>>(Wo, wqkvoT + (size_t)1536*Isz, Isz, 512, 1.f);
  transpose_cast<<<dim3(Isz / 32, 512 / 32), tb, 0, stream>>>(W_out, woutT, 512, Isz, 1.f);
  transpose_cast<<<dim3(Dsz / 32, Isz / 32), tb, 0, stream>>>(W_down, wdownT, Isz, Dsz, 1.f);
  build_wift<<<96, 256, 0, stream>>>(Wi, Wf, wifT);

  ln_kernel<<<NTOK, 256, 0, stream>>>(x, ln_g, ln_b, hbuf);

  gemm_bt<0><<<dim3(Isz / 128, NTOK / 128), 256, 0, stream>>>(hbuf, wupT, ubuf, nullptr, NTOK, Isz, Dsz);
  gemm_bt<4><<<dim3(2048 / 128, NTOK / 128), 256, 0, stream>>>(ubuf, wqkvoT, qkvob, bo, NTOK, 2048, Isz);

  ifproj_mfma<<<NTOK / 128, 256, 0, stream>>>(ubuf, wifT, bi, bfv, ifb);
  kv_transpose<<<NBH * NCH, 256, 0, stream>>>(qkvob, kTg, vTg);

  gates_a<<<NBH * NCH, 64, 0, stream>>>(ifb, bloc, Mh);
  gates_b<<<1, 32, 0, stream>>>(bloc, Mh, mst, decays, mendb);
  chunk_inc_mfma<<<NBH * NCH, 256, 0, stream>>>(kTg, vTg, ifb, bloc, mendb, Gbuf, ngbuf);
  state_scan<<<520, 256, 0, stream>>>(Gbuf, ngbuf, decays, CstB, nst);
  intra_mfma<<<NBH * NCH, 256, 0, stream>>>(qkvob, vTg, CstB, nst, ifb, bloc, Mh, mst, htbuf);

  gn_gate<<<NTOK * Hn / 4, 256, 0, stream>>>(htbuf, qkvob, mh_g, gbuf);
  gemm_bt<0><<<dim3(Isz / 128, NTOK / 128), 256, 0, stream>>>(gbuf, woutT, ybuf, nullptr, NTOK, Isz, 512);
  gemm_bt<3><<<dim3(Dsz / 128, NTOK / 128), 256, 0, stream>>>(ybuf, wdownT, (float*)d_out, x, NTOK, Dsz, Isz);
}

// Round 4
// 265.408 us; speedup vs baseline: 2.1199x; 1.1799x over previous
//
#include <hip/hip_runtime.h>
#include <hip/hip_bf16.h>
#include <stdint.h>
#include <stddef.h>

typedef __bf16 bf16_t;
typedef __bf16 bf16x4 __attribute__((ext_vector_type(4)));
typedef __bf16 bf16x8 __attribute__((ext_vector_type(8)));
typedef float  f32x4  __attribute__((ext_vector_type(4)));

#define Bsz  4
#define Ssz  2048
#define Dsz  768
#define Isz  1536
#define Hn   8
#define HDsz 64
#define NTOK (Bsz*Ssz)      /* 8192 */
#define Lc   64
#define NCH  (Ssz/Lc)       /* 32 */
#define NBH  (Bsz*Hn)       /* 32 */

/* ---------------- workspace layout (bytes) ---------------- */
#define OFF_H      ((size_t)0)                    /* ln out bf16 12.58M; CstB aliases after up-gemm */
#define OFF_WUPT   ((size_t)12582912)
#define OFF_WQKVO  ((size_t)14942208)             /* 2048x1536 bf16 */
#define OFF_WOUTT  ((size_t)21233664)
#define OFF_WDOWNT ((size_t)22806528)
#define OFF_U      ((size_t)25165824)             /* 25.17M; HT/G/gated alias after u dead */
#define OFF_QKVO   ((size_t)50331648)             /* 8192x2048 bf16; y aliases */
#define OFF_KT     ((size_t)83886080)             /* [bh][64][2048] bf16 */
#define OFF_VT     ((size_t)92274688)
#define OFF_IFB    ((size_t)100663296)
#define OFF_BLOC   ((size_t)101187584)
#define OFF_MHAT   ((size_t)101449728)
#define OFF_MST    ((size_t)101711872)
#define OFF_DEC    ((size_t)101715968)
#define OFF_MEND   ((size_t)101720064)
#define OFF_NG     ((size_t)101724160)
#define OFF_NST    ((size_t)101986304)
#define OFF_WIFT   ((size_t)102248448)            /* 16x1536 bf16 */
/* aliases */
#define OFF_CSTB   ((size_t)0)                    /* 32*32*4096 bf16 = 8.39M (over H) */
#define OFF_HT     OFF_U                          /* 8192*512 f32 = 16.78M */
#define OFF_G      OFF_U                          /* 32*32*4096 bf16 = 8.39M */
#define OFF_GATED  (OFF_U + 16777216)             /* 8192*512 bf16 = 8.39M */
#define OFF_Y      OFF_QKVO                       /* 8192*1536 bf16 */

/* ---------------- helpers ---------------- */
__device__ __forceinline__ void gload16(const void* gsrc, void* ldst) {
  __builtin_amdgcn_global_load_lds(
      (const __attribute__((address_space(1))) void*)gsrc,
      (__attribute__((address_space(3))) void*)ldst, 16, 0, 0);
}

__device__ __forceinline__ float blockReduceSum256(float v) {
  #pragma unroll
  for (int o = 1; o < 64; o <<= 1) v += __shfl_xor(v, o, 64);
  __shared__ float sh[4];
  int wid = threadIdx.x >> 6;
  __syncthreads();
  if ((threadIdx.x & 63) == 0) sh[wid] = v;
  __syncthreads();
  return sh[0] + sh[1] + sh[2] + sh[3];
}

/* ---------------- weight transpose+cast: W (K,N) f32 -> Wt (N,K) bf16, *scale ---------------- */
__global__ __launch_bounds__(256) void transpose_cast(const float* __restrict__ W,
                                                      bf16_t* __restrict__ Wt,
                                                      int K, int N, float scale) {
  __shared__ float tile[32][33];
  int n0 = blockIdx.x * 32, k0 = blockIdx.y * 32;
  int tx = threadIdx.x, ty = threadIdx.y;   /* block (32,8) */
  #pragma unroll
  for (int j = 0; j < 32; j += 8)
    tile[ty + j][tx] = W[(size_t)(k0 + ty + j) * N + n0 + tx];
  __syncthreads();
  #pragma unroll
  for (int j = 0; j < 32; j += 8)
    Wt[(size_t)(n0 + ty + j) * K + k0 + tx] = (bf16_t)(tile[tx][ty + j] * scale);
}

/* ---------------- build WifT: [16][1536] bf16 (rows 0-7 Wi^T, 8-15 Wf^T) ---------------- */
__global__ __launch_bounds__(256) void build_wift(const float* __restrict__ Wi,
                                                  const float* __restrict__ Wf,
                                                  bf16_t* __restrict__ WifT) {
  int idx = blockIdx.x * 256 + threadIdx.x;   /* 96 blocks */
  if (idx < 16 * 1536) {
    int n = idx / 1536, k = idx - n * 1536;
    float v = (n < 8) ? Wi[(size_t)k * 8 + n] : Wf[(size_t)k * 8 + (n - 8)];
    WifT[idx] = (bf16_t)v;
  }
}

/* ---------------- LayerNorm: x f32 (tok,768) -> h bf16 ---------------- */
__global__ __launch_bounds__(256) void ln_kernel(const float* __restrict__ x,
                                                 const float* __restrict__ g,
                                                 const float* __restrict__ bta,
                                                 bf16_t* __restrict__ h) {
  size_t tok = blockIdx.x;
  const float* xr = x + tok * Dsz;
  int t = threadIdx.x;
  float v[3]; float s = 0.f;
  #pragma unroll
  for (int i = 0; i < 3; ++i) { v[i] = xr[t + 256 * i]; s += v[i]; }
  s = blockReduceSum256(s);
  float mu = s * (1.f / Dsz);
  float s2 = 0.f;
  #pragma unroll
  for (int i = 0; i < 3; ++i) { float d = v[i] - mu; s2 += d * d; }
  s2 = blockReduceSum256(s2);
  float rs = rsqrtf(s2 * (1.f / Dsz) + 1e-5f);
  #pragma unroll
  for (int i = 0; i < 3; ++i) {
    int col = t + 256 * i;
    h[tok * Dsz + col] = (bf16_t)((v[i] - mu) * rs * g[col] + bta[col]);
  }
}

/* ======================================================================
   256x256 counted-vmcnt pipelined GEMM: C(M,N) = A(M,K) @ Bt(N,K)^T
   512 threads = 8 waves (2M x 4N); BK=32; 4-slot LDS ring (128 KiB);
   staging via global_load_lds w/ pre-swizzled source; entry gate
   s_waitcnt vmcnt(8) + raw s_barrier (never vmcnt(0) in the loop).
   Swizzle: byte ^= ((row>>1)&3)<<4 on 64B rows (both-sides involution).
   EPI: 0 = bf16 out; 4 = qkvo (col>=1536: sigmoid(acc+bo)).
   ====================================================================== */
template<int EPI>
__global__ __launch_bounds__(512, 2) void gemm256(const bf16_t* __restrict__ A,
                                                  const bf16_t* __restrict__ Bt,
                                                  void* __restrict__ Cout,
                                                  const void* __restrict__ extra,
                                                  int M, int N, int K) {
  __shared__ bf16_t As[4][256 * 32];
  __shared__ bf16_t Bs[4][256 * 32];
  const int t = threadIdx.x;
  const int wid = t >> 6, l = t & 63;
  const int wm = wid >> 2, wn = wid & 3;
  const int l15 = l & 15, l4 = l >> 4;

  /* bijective XCD swizzle (nwg % 8 == 0 for all launches) */
  const int gx = gridDim.x;
  const int nwg = gx * gridDim.y;
  const int cpx = nwg >> 3;
  int bid = blockIdx.y * gx + blockIdx.x;
  int wg = (bid & 7) * cpx + (bid >> 3);
  const int tile_m = (wg / gx) * 256;
  const int tile_n = (wg % gx) * 256;

  const int sr = t >> 2;              /* staging row base (issue i adds 128) */
  const int scb = (t & 3) * 16;       /* dest byte col within 64B row */

  f32x4 acc[8][4];
  #pragma unroll
  for (int m = 0; m < 8; ++m)
    #pragma unroll
    for (int n = 0; n < 4; ++n) acc[m][n] = (f32x4){0.f, 0.f, 0.f, 0.f};

  const int KT = K >> 5;

#define STAGE_A(tau) do { int s_ = (tau) & 3; int k0_ = (tau) << 5;           \
    _Pragma("unroll")                                                          \
    for (int i_ = 0; i_ < 2; ++i_) {                                           \
      int r_ = sr + i_ * 128;                                                  \
      int cs_ = scb ^ (((r_ >> 1) & 3) << 4);                                  \
      gload16(A + (size_t)(tile_m + r_) * K + k0_ + (cs_ >> 1),                \
              (char*)&As[s_][0] + i_ * 8192 + t * 16);                         \
    } } while (0)
#define STAGE_B(tau) do { int s_ = (tau) & 3; int k0_ = (tau) << 5;           \
    _Pragma("unroll")                                                          \
    for (int i_ = 0; i_ < 2; ++i_) {                                           \
      int r_ = sr + i_ * 128;                                                  \
      int cs_ = scb ^ (((r_ >> 1) & 3) << 4);                                  \
      gload16(Bt + (size_t)(tile_n + r_) * K + k0_ + (cs_ >> 1),               \
              (char*)&Bs[s_][0] + i_ * 8192 + t * 16);                         \
    } } while (0)

  /* prologue: 3 K-tiles in flight (12 loads/thread) */
  STAGE_A(0); STAGE_B(0); STAGE_A(1); STAGE_B(1); STAGE_A(2); STAGE_B(2);

  for (int tau = 0; tau < KT; ++tau) {
    const int s = tau & 3;
    /* entry gate: last 8 outstanding = tiles tau+1,tau+2 -> slot s landed */
    asm volatile("s_waitcnt vmcnt(8)" ::: "memory");
    __builtin_amdgcn_s_barrier();
    __builtin_amdgcn_sched_barrier(0);

    bf16x8 bF[4], aF[4];
    #pragma unroll
    for (int n = 0; n < 4; ++n) {
      int r = wn * 64 + n * 16 + l15;
      int cb = (l4 * 16) ^ (((r >> 1) & 3) << 4);
      bF[n] = *(const bf16x8*)((const char*)&Bs[s][0] + r * 64 + cb);
    }
    #pragma unroll
    for (int m = 0; m < 4; ++m) {
      int r = wm * 128 + m * 16 + l15;
      int cb = (l4 * 16) ^ (((r >> 1) & 3) << 4);
      aF[m] = *(const bf16x8*)((const char*)&As[s][0] + r * 64 + cb);
    }
    if (tau + 3 < KT) STAGE_A(tau + 3);
    __builtin_amdgcn_s_barrier();
    __builtin_amdgcn_s_setprio(1);
    #pragma unroll
    for (int m = 0; m < 4; ++m)
      #pragma unroll
      for (int n = 0; n < 4; ++n)
        acc[m][n] = __builtin_amdgcn_mfma_f32_16x16x32_bf16(aF[m], bF[n], acc[m][n], 0, 0, 0);
    __builtin_amdgcn_s_setprio(0);

    #pragma unroll
    for (int m = 0; m < 4; ++m) {
      int r = wm * 128 + (m + 4) * 16 + l15;
      int cb = (l4 * 16) ^ (((r >> 1) & 3) << 4);
      aF[m] = *(const bf16x8*)((const char*)&As[s][0] + r * 64 + cb);
    }
    if (tau + 3 < KT) STAGE_B(tau + 3);
    __builtin_amdgcn_s_barrier();
    __builtin_amdgcn_s_setprio(1);
    #pragma unroll
    for (int m = 0; m < 4; ++m)
      #pragma unroll
      for (int n = 0; n < 4; ++n)
        acc[m + 4][n] = __builtin_amdgcn_mfma_f32_16x16x32_bf16(aF[m], bF[n], acc[m + 4][n], 0, 0, 0);
    __builtin_amdgcn_s_setprio(0);
  }
#undef STAGE_A
#undef STAGE_B

  const int rbase = tile_m + wm * 128 + l4 * 4;
  const int cbase = tile_n + wn * 64 + l15;
  #pragma unroll
  for (int m = 0; m < 8; ++m)
    #pragma unroll
    for (int n = 0; n < 4; ++n)
      #pragma unroll
      for (int j = 0; j < 4; ++j) {
        int row = rbase + m * 16 + j;
        int col = cbase + n * 16;
        float v = acc[m][n][j];
        if constexpr (EPI == 0) {
          ((bf16_t*)Cout)[(size_t)row * N + col] = (bf16_t)v;
        } else {  /* EPI == 4 */
          if (col < 1536) {
            ((bf16_t*)Cout)[(size_t)row * N + col] = (bf16_t)v;
          } else {
            float z = v + ((const float*)extra)[col - 1536];
            ((bf16_t*)Cout)[(size_t)row * N + col] = (bf16_t)(1.f / (1.f + __expf(-z)));
          }
        }
      }
}

/* ---------------- 128^2 MFMA GEMM (down-proj only): EPI 3 = f32 out + resid ---------------- */
template<int EPI>
__global__ __launch_bounds__(256) void gemm_bt(const bf16_t* __restrict__ A,
                                               const bf16_t* __restrict__ Bt,
                                               void* __restrict__ Cout,
                                               const void* __restrict__ extra,
                                               int M, int N, int K) {
  __shared__ bf16_t As[128 * 64];
  __shared__ bf16_t Bs[128 * 64];
  const int t = threadIdx.x;
  const int w = t >> 6, l = t & 63;
  const int tile_m = blockIdx.y * 128, tile_n = blockIdx.x * 128;
  const int wr = w >> 1, wc = w & 1;
  const int lrow = l >> 3, lk = (l & 7) * 8;
  const int l15 = l & 15, l4 = l >> 4;

  f32x4 acc[4][4];
  #pragma unroll
  for (int m = 0; m < 4; ++m)
    #pragma unroll
    for (int n = 0; n < 4; ++n) acc[m][n] = (f32x4){0.f, 0.f, 0.f, 0.f};

  for (int k0 = 0; k0 < K; k0 += 64) {
    #pragma unroll
    for (int i = 0; i < 4; ++i) {
      int ch = w * 4 + i;
      int row = ch * 8 + lrow;
      gload16(A  + (size_t)(tile_m + row) * K + k0 + lk, &As[ch * 512]);
      gload16(Bt + (size_t)(tile_n + row) * K + k0 + lk, &Bs[ch * 512]);
    }
    __syncthreads();
    #pragma unroll
    for (int kk = 0; kk < 2; ++kk) {
      bf16x8 af[4], bfr[4];
      #pragma unroll
      for (int m = 0; m < 4; ++m)
        af[m] = *(const bf16x8*)&As[(wr * 64 + m * 16 + l15) * 64 + kk * 32 + l4 * 8];
      #pragma unroll
      for (int n = 0; n < 4; ++n)
        bfr[n] = *(const bf16x8*)&Bs[(wc * 64 + n * 16 + l15) * 64 + kk * 32 + l4 * 8];
      #pragma unroll
      for (int m = 0; m < 4; ++m)
        #pragma unroll
        for (int n = 0; n < 4; ++n)
          acc[m][n] = __builtin_amdgcn_mfma_f32_16x16x32_bf16(af[m], bfr[n], acc[m][n], 0, 0, 0);
    }
    __syncthreads();
  }

  const int rbase = tile_m + wr * 64 + l4 * 4;
  const int cbase = tile_n + wc * 64 + l15;
  #pragma unroll
  for (int m = 0; m < 4; ++m)
    #pragma unroll
    for (int n = 0; n < 4; ++n)
      #pragma unroll
      for (int j = 0; j < 4; ++j) {
        int row = rbase + m * 16 + j;
        int col = cbase + n * 16;
        float v = acc[m][n][j];
        if constexpr (EPI == 0) {
          ((bf16_t*)Cout)[(size_t)row * N + col] = (bf16_t)v;
        } else {
          ((float*)Cout)[(size_t)row * N + col] =
              v + ((const float*)extra)[(size_t)row * N + col];
        }
      }
}

/* ---------------- i/f gate projection as tiny MFMA GEMM: M=8192 N=16 K=1536 ---------------- */
__global__ __launch_bounds__(256) void ifproj_mfma(const bf16_t* __restrict__ u,
                                                   const bf16_t* __restrict__ WifT,
                                                   const float* __restrict__ bi,
                                                   const float* __restrict__ bfv,
                                                   float* __restrict__ ifb) {
  __shared__ bf16_t As[128 * 64];
  __shared__ bf16_t Bs[16 * 64];
  const int t = threadIdx.x, w = t >> 6, l = t & 63;
  const int l15 = l & 15, l4 = l >> 4;
  const int lrow = l >> 3, lk = (l & 7) * 8;
  const int tile_m = blockIdx.x * 128;
  f32x4 acc[2];
  acc[0] = (f32x4){0.f, 0.f, 0.f, 0.f};
  acc[1] = (f32x4){0.f, 0.f, 0.f, 0.f};

  for (int k0 = 0; k0 < Isz; k0 += 64) {
    #pragma unroll
    for (int i = 0; i < 4; ++i) {
      int ch = w * 4 + i;
      int row = ch * 8 + lrow;
      gload16(u + (size_t)(tile_m + row) * Isz + k0 + lk, &As[ch * 512]);
    }
    if (t < 128) {
      int rr = t >> 3, c0 = (t & 7) * 8;
      *(bf16x8*)&Bs[rr * 64 + c0] = *(const bf16x8*)(WifT + (size_t)rr * Isz + k0 + c0);
    }
    __syncthreads();
    #pragma unroll
    for (int kk = 0; kk < 2; ++kk) {
      bf16x8 bfr = *(const bf16x8*)&Bs[l15 * 64 + kk * 32 + l4 * 8];
      #pragma unroll
      for (int m = 0; m < 2; ++m) {
        bf16x8 af = *(const bf16x8*)&As[(w * 32 + m * 16 + l15) * 64 + kk * 32 + l4 * 8];
        acc[m] = __builtin_amdgcn_mfma_f32_16x16x32_bf16(af, bfr, acc[m], 0, 0, 0);
      }
    }
    __syncthreads();
  }
  float bias = (l15 < 8) ? bi[l15] : bfv[l15 - 8];
  #pragma unroll
  for (int m = 0; m < 2; ++m)
    #pragma unroll
    for (int j = 0; j < 4; ++j) {
      int row = tile_m + w * 32 + m * 16 + l4 * 4 + j;
      ifb[(size_t)row * 16 + l15] = acc[m][j] + bias;
    }
}

/* ---------------- gates pass A: per (bh,chunk) local cumsum + prefix-max ---------------- */
__global__ __launch_bounds__(64) void gates_a(const float* __restrict__ ifb,
                                              float* __restrict__ blocal,
                                              float* __restrict__ Mhat) {
  int bh = blockIdx.x >> 5, c = blockIdx.x & 31;
  int b = bh >> 3, h = bh & 7;
  int lane = threadIdx.x;
  size_t tok = (size_t)b * Ssz + c * Lc + lane;
  float iv = ifb[tok * 16 + h];
  float fv = ifb[tok * 16 + 8 + h];
  float bt = fv;
  #pragma unroll
  for (int d = 1; d < 64; d <<= 1) { float o = __shfl_up(bt, d, 64); if (lane >= d) bt += o; }
  float a = iv - bt;
  float pm = a;
  #pragma unroll
  for (int d = 1; d < 64; d <<= 1) { float o = __shfl_up(pm, d, 64); if (lane >= d) pm = fmaxf(pm, o); }
  blocal[(size_t)bh * Ssz + c * Lc + lane] = bt;
  Mhat[(size_t)bh * Ssz + c * Lc + lane] = bt + pm;
}

/* ---------------- gates pass B: sequential chunk-boundary m recurrence + decays ---------------- */
__global__ void gates_b(const float* __restrict__ blocal, const float* __restrict__ Mhat,
                        float* __restrict__ mstart, float* __restrict__ decays,
                        float* __restrict__ mend) {
  int bh = threadIdx.x;
  if (bh < NBH) {
    float M = 0.f;
    for (int c = 0; c < NCH; ++c) {
      mstart[bh * NCH + c] = M;
      float bL = blocal[(size_t)bh * Ssz + c * Lc + 63];
      float Mh = Mhat[(size_t)bh * Ssz + c * Lc + 63];
      float Mn = fmaxf(M + bL, Mh);
      decays[bh * NCH + c] = __expf(M + bL - Mn);
      mend[bh * NCH + c] = Mn;
      M = Mn;
    }
  }
}

/* ---------------- k/v transpose: qkvo cols -> kT/vT [bh][64 d][2048 s] bf16 ---------------- */
__global__ __launch_bounds__(256) void kv_transpose(const bf16_t* __restrict__ qkvo,
                                                    bf16_t* __restrict__ kTg,
                                                    bf16_t* __restrict__ vTg) {
  int bh = blockIdx.x >> 5, st = blockIdx.x & 31;
  int b = bh >> 3, h = bh & 7;
  __shared__ bf16_t Lk[64 * 72];
  __shared__ bf16_t Lv[64 * 72];
  int t = threadIdx.x;
  size_t tok0 = (size_t)b * Ssz + st * 64;
  #pragma unroll
  for (int i = 0; i < 2; ++i) {
    int e = t + i * 256; int r = e >> 3, c0 = (e & 7) * 8;
    bf16x8 kv = *(const bf16x8*)(qkvo + (tok0 + r) * 2048 + 512 + h * 64 + c0);
    bf16x8 vv = *(const bf16x8*)(qkvo + (tok0 + r) * 2048 + 1024 + h * 64 + c0);
    *(bf16x8*)&Lk[r * 72 + c0] = kv;
    *(bf16x8*)&Lv[r * 72 + c0] = vv;
  }
  __syncthreads();
  #pragma unroll
  for (int i = 0; i < 2; ++i) {
    int e = t + i * 256; int d = e >> 3, s0 = (e & 7) * 8;
    bf16x8 ok, ov;
    #pragma unroll
    for (int j = 0; j < 8; ++j) {
      ok[j] = Lk[(s0 + j) * 72 + d];
      ov[j] = Lv[(s0 + j) * 72 + d];
    }
    *(bf16x8*)(kTg + ((size_t)bh * 64 + d) * Ssz + st * 64 + s0) = ok;
    *(bf16x8*)(vTg + ((size_t)bh * 64 + d) * Ssz + st * 64 + s0) = ov;
  }
}

/* ---------------- per-chunk state increment, MFMA ---------------- */
__global__ __launch_bounds__(256) void chunk_inc_mfma(const bf16_t* __restrict__ kTg,
                                                      const bf16_t* __restrict__ vTg,
                                                      const float* __restrict__ ifb,
                                                      const float* __restrict__ blocal,
                                                      const float* __restrict__ mend,
                                                      bf16_t* __restrict__ G,
                                                      float* __restrict__ ng) {
  int bh = blockIdx.x >> 5, c = blockIdx.x & 31;
  int b = bh >> 3, h = bh & 7;
  __shared__ bf16_t Vt[64 * 64];   /* [v][s] */
  __shared__ bf16_t Kw[64 * 64];   /* [k][s] pre-weighted by w_s */
  __shared__ float wsh[64];
  const int t = threadIdx.x, w = t >> 6, l = t & 63;
  const int l15 = l & 15, l4 = l >> 4;
  if (t < 64) {
    float mL = mend[bh * NCH + c];
    float bL = blocal[(size_t)bh * Ssz + c * Lc + 63];
    float bt = blocal[(size_t)bh * Ssz + c * Lc + t];
    float iv = ifb[((size_t)b * Ssz + c * Lc + t) * 16 + h];
    wsh[t] = __expf(iv + bL - bt - mL);
  }
  __syncthreads();
  {
    const int r = l >> 3, c8 = (l & 7) * 8;
    #pragma unroll
    for (int i = 0; i < 2; ++i) {
      int seg = w * 2 + i, row = seg * 8 + r;
      gload16(vTg + ((size_t)bh * 64 + row) * Ssz + c * 64 + c8, &Vt[seg * 512]);
    }
    #pragma unroll
    for (int i = 0; i < 2; ++i) {
      int e = t + i * 256; int row = e >> 3, c0 = (e & 7) * 8;
      bf16x8 kv = *(const bf16x8*)(kTg + ((size_t)bh * 64 + row) * Ssz + c * 64 + c0);
      #pragma unroll
      for (int j = 0; j < 8; ++j) kv[j] = (bf16_t)((float)kv[j] * wsh[c0 + j]);
      *(bf16x8*)&Kw[row * 64 + c0] = kv;
    }
  }
  __syncthreads();
  f32x4 acc[4];
  #pragma unroll
  for (int n = 0; n < 4; ++n) acc[n] = (f32x4){0.f, 0.f, 0.f, 0.f};
  #pragma unroll
  for (int kk = 0; kk < 2; ++kk) {
    bf16x8 af = *(const bf16x8*)&Vt[(w * 16 + l15) * 64 + kk * 32 + l4 * 8];
    #pragma unroll
    for (int n = 0; n < 4; ++n) {
      bf16x8 bfr = *(const bf16x8*)&Kw[(n * 16 + l15) * 64 + kk * 32 + l4 * 8];
      acc[n] = __builtin_amdgcn_mfma_f32_16x16x32_bf16(af, bfr, acc[n], 0, 0, 0);
    }
  }
  size_t gb = ((size_t)bh * NCH + c) * 4096;
  #pragma unroll
  for (int n = 0; n < 4; ++n)
    #pragma unroll
    for (int j = 0; j < 4; ++j) {
      int row = w * 16 + l4 * 4 + j;
      int col = n * 16 + l15;
      G[gb + (size_t)row * 64 + col] = (bf16_t)acc[n][j];
    }
  if (t < 64) {
    float s = 0.f;
    for (int s2 = 0; s2 < 64; ++s2) s += (float)Kw[t * 64 + s2];
    ng[((size_t)bh * NCH + c) * 64 + t] = s;
  }
}

/* ---------------- state scan: per-element 32-step recurrence (parallel) ---------------- */
__global__ __launch_bounds__(256) void state_scan(const bf16_t* __restrict__ G,
                                                  const float* __restrict__ ng,
                                                  const float* __restrict__ decays,
                                                  bf16_t* __restrict__ CstB,
                                                  float* __restrict__ nst) {
  int gid = blockIdx.x;
  if (gid < 512) {
    int idx = gid * 256 + threadIdx.x;
    int bh = idx >> 12, e = idx & 4095;
    const float* d = decays + bh * NCH;
    float C = 0.f;
    #pragma unroll
    for (int c = 0; c < NCH; ++c) {
      size_t o = ((size_t)bh * NCH + c) * 4096 + e;
      CstB[o] = (bf16_t)C;
      C = d[c] * C + (float)G[o];
    }
  } else {
    int idx = (gid - 512) * 256 + threadIdx.x;
    int bh = idx >> 6, e = idx & 63;
    const float* d = decays + bh * NCH;
    float n = 0.f;
    #pragma unroll
    for (int c = 0; c < NCH; ++c) {
      size_t o = ((size_t)bh * NCH + c) * 64 + e;
      nst[o] = n;
      n = d[c] * n + ng[o];
    }
  }
}

/* ---------------- intra-chunk outputs, MFMA ---------------- */
__global__ __launch_bounds__(256) void intra_mfma(const bf16_t* __restrict__ qkvo,
                                                  const bf16_t* __restrict__ vTg,
                                                  const bf16_t* __restrict__ CstB,
                                                  const float* __restrict__ nst,
                                                  const float* __restrict__ ifb,
                                                  const float* __restrict__ blocal,
                                                  const float* __restrict__ Mhat,
                                                  const float* __restrict__ mstart,
                                                  float* __restrict__ ht) {
  int bh = blockIdx.x >> 5, c = blockIdx.x & 31;
  int b = bh >> 3, h = bh & 7;
  __shared__ bf16_t qs[64 * 64];
  __shared__ bf16_t ks[64 * 64];    /* aliased as P after QK^T */
  __shared__ bf16_t vTs[64 * 64];
  __shared__ bf16_t Cs[64 * 64];
  __shared__ float nin[64], den_s[64], ssrc[64], sdst[64], esc[64];
  const int t = threadIdx.x, w = t >> 6, l = t & 63;
  const int l15 = l & 15, l4 = l >> 4;
  const size_t tok0 = (size_t)b * Ssz + c * Lc;
  const size_t cbase = ((size_t)bh * NCH + c) * 4096;

  if (t < 64) {
    nin[t] = nst[((size_t)bh * NCH + c) * 64 + t];
    float bt = blocal[(size_t)bh * Ssz + c * Lc + t];
    float Mh2 = Mhat[(size_t)bh * Ssz + c * Lc + t];
    float Mc = mstart[bh * NCH + c];
    float iv = ifb[(tok0 + t) * 16 + h];
    float mt = fmaxf(Mc + bt, Mh2);
    ssrc[t] = iv - bt;
    sdst[t] = bt - mt;
    esc[t]  = __expf(Mc + bt - mt);
  }
  {
    const int r = l >> 3, c8 = (l & 7) * 8;
    #pragma unroll
    for (int i = 0; i < 2; ++i) {
      int seg = w * 2 + i, row = seg * 8 + r;
      gload16(qkvo + (tok0 + row) * 2048 + h * 64 + c8,          &qs[seg * 512]);
      gload16(qkvo + (tok0 + row) * 2048 + 512 + h * 64 + c8,    &ks[seg * 512]);
      gload16(vTg + ((size_t)bh * 64 + row) * Ssz + c * 64 + c8, &vTs[seg * 512]);
      gload16(CstB + cbase + seg * 512 + l * 8,                  &Cs[seg * 512]);
    }
  }
  __syncthreads();

  f32x4 aS[4];
  #pragma unroll
  for (int n = 0; n < 4; ++n) aS[n] = (f32x4){0.f, 0.f, 0.f, 0.f};
  #pragma unroll
  for (int kk = 0; kk < 2; ++kk) {
    bf16x8 af = *(const bf16x8*)&qs[(w * 16 + l15) * 64 + kk * 32 + l4 * 8];
    #pragma unroll
    for (int n = 0; n < 4; ++n) {
      bf16x8 bfr = *(const bf16x8*)&ks[(n * 16 + l15) * 64 + kk * 32 + l4 * 8];
      aS[n] = __builtin_amdgcn_mfma_f32_16x16x32_bf16(af, bfr, aS[n], 0, 0, 0);
    }
  }
  {
    int row = w * 16 + (l >> 2);
    int c0 = (l & 3) * 16;
    float e = esc[row];
    #pragma unroll
    for (int i2 = 0; i2 < 2; ++i2) {
      bf16x8 v8 = *(const bf16x8*)&qs[row * 64 + c0 + i2 * 8];
      #pragma unroll
      for (int j = 0; j < 8; ++j) v8[j] = (bf16_t)((float)v8[j] * e);
      *(bf16x8*)&qs[row * 64 + c0 + i2 * 8] = v8;
    }
  }
  float rs[4] = {0.f, 0.f, 0.f, 0.f};
  #pragma unroll
  for (int n = 0; n < 4; ++n) {
    int col = n * 16 + l15;
    float es = ssrc[col];
    #pragma unroll
    for (int j = 0; j < 4; ++j) {
      int row = w * 16 + l4 * 4 + j;
      float p = (col <= row) ? aS[n][j] * __expf(es + sdst[row]) : 0.f;
      aS[n][j] = p;
      rs[j] += p;
    }
  }
  #pragma unroll
  for (int j = 0; j < 4; ++j) {
    rs[j] += __shfl_xor(rs[j], 1, 64);
    rs[j] += __shfl_xor(rs[j], 2, 64);
    rs[j] += __shfl_xor(rs[j], 4, 64);
    rs[j] += __shfl_xor(rs[j], 8, 64);
  }
  if (l15 == 0) {
    #pragma unroll
    for (int j = 0; j < 4; ++j) den_s[w * 16 + l4 * 4 + j] = rs[j];
  }
  __syncthreads();

  #pragma unroll
  for (int n = 0; n < 4; ++n)
    #pragma unroll
    for (int j = 0; j < 4; ++j)
      ks[(w * 16 + l4 * 4 + j) * 64 + n * 16 + l15] = (bf16_t)aS[n][j];

  {
    int row = w * 16 + (l >> 2);
    int c0 = (l & 3) * 16;
    float part = 0.f;
    #pragma unroll
    for (int i2 = 0; i2 < 16; ++i2)
      part += (float)qs[row * 64 + c0 + i2] * nin[c0 + i2];
    part += __shfl_xor(part, 1, 64);
    part += __shfl_xor(part, 2, 64);
    if ((l & 3) == 0)
      den_s[row] = fmaxf(fabsf(den_s[row] + part), 1.0f);
  }
  __syncthreads();

  f32x4 aO[4];
  #pragma unroll
  for (int n = 0; n < 4; ++n) aO[n] = (f32x4){0.f, 0.f, 0.f, 0.f};
  #pragma unroll
  for (int kk = 0; kk < 2; ++kk) {
    bf16x8 afP = *(const bf16x8*)&ks[(w * 16 + l15) * 64 + kk * 32 + l4 * 8];
    bf16x8 afQ = *(const bf16x8*)&qs[(w * 16 + l15) * 64 + kk * 32 + l4 * 8];
    #pragma unroll
    for (int n = 0; n < 4; ++n) {
      bf16x8 bV = *(const bf16x8*)&vTs[(n * 16 + l15) * 64 + kk * 32 + l4 * 8];
      bf16x8 bC = *(const bf16x8*)&Cs[(n * 16 + l15) * 64 + kk * 32 + l4 * 8];
      aO[n] = __builtin_amdgcn_mfma_f32_16x16x32_bf16(afP, bV, aO[n], 0, 0, 0);
      aO[n] = __builtin_amdgcn_mfma_f32_16x16x32_bf16(afQ, bC, aO[n], 0, 0, 0);
    }
  }
  #pragma unroll
  for (int j = 0; j < 4; ++j) {
    int row = w * 16 + l4 * 4 + j;
    float rinv = 1.f / den_s[row];
    size_t rowg = ((tok0 + row) * Hn + h) * HDsz;
    #pragma unroll
    for (int n = 0; n < 4; ++n)
      ht[rowg + n * 16 + l15] = aO[n][j] * rinv;
  }
}

/* ---------------- group-norm + output gate ---------------- */
__global__ __launch_bounds__(256) void gn_gate(const float* __restrict__ ht,
                                               const bf16_t* __restrict__ qkvo,
                                               const float* __restrict__ mhg,
                                               bf16_t* __restrict__ gated) {
  int gid = blockIdx.x * 4 + (threadIdx.x >> 6);
  int lane = threadIdx.x & 63;
  int h = gid & 7;
  size_t tok = (size_t)(gid >> 3);
  size_t idx = (size_t)gid * 64 + lane;
  float v = ht[idx];
  float s = v;
  #pragma unroll
  for (int o = 1; o < 64; o <<= 1) s += __shfl_xor(s, o, 64);
  float mu = s * (1.f / 64.f);
  float d = v - mu;
  float s2 = d * d;
  #pragma unroll
  for (int o = 1; o < 64; o <<= 1) s2 += __shfl_xor(s2, o, 64);
  float hn = d * rsqrtf(s2 * (1.f / 64.f) + 1e-5f) * mhg[h * 64 + lane];
  float og = (float)qkvo[tok * 2048 + 1536 + h * 64 + lane];
  gated[idx] = (bf16_t)(og * hn);
}

/* ---------------- launcher ---------------- */
extern "C" void kernel_launch(void* const* d_in, const int* in_sizes, int n_in,
                              void* d_out, int out_size, void* d_ws, size_t ws_size,
                              hipStream_t stream) {
  const float* x     = (const float*)d_in[0];
  const float* ln_g  = (const float*)d_in[1];
  const float* ln_b  = (const float*)d_in[2];
  const float* W_up  = (const float*)d_in[3];
  const float* W_down= (const float*)d_in[4];
  const float* Wq    = (const float*)d_in[5];
  const float* Wk    = (const float*)d_in[6];
  const float* Wv    = (const float*)d_in[7];
  const float* Wi    = (const float*)d_in[8];
  const float* bi    = (const float*)d_in[9];
  const float* Wf    = (const float*)d_in[10];
  const float* bfv   = (const float*)d_in[11];
  const float* Wo    = (const float*)d_in[12];
  const float* bo    = (const float*)d_in[13];
  const float* mh_g  = (const float*)d_in[14];
  const float* W_out = (const float*)d_in[15];

  char* ws = (char*)d_ws;
  bf16_t* hbuf   = (bf16_t*)(ws + OFF_H);
  bf16_t* wupT   = (bf16_t*)(ws + OFF_WUPT);
  bf16_t* wqkvoT = (bf16_t*)(ws + OFF_WQKVO);
  bf16_t* woutT  = (bf16_t*)(ws + OFF_WOUTT);
  bf16_t* wdownT = (bf16_t*)(ws + OFF_WDOWNT);
  bf16_t* ubuf   = (bf16_t*)(ws + OFF_U);
  bf16_t* qkvob  = (bf16_t*)(ws + OFF_QKVO);
  bf16_t* kTg    = (bf16_t*)(ws + OFF_KT);
  bf16_t* vTg    = (bf16_t*)(ws + OFF_VT);
  float*  ifb    = (float*)(ws + OFF_IFB);
  float*  bloc   = (float*)(ws + OFF_BLOC);
  float*  Mh     = (float*)(ws + OFF_MHAT);
  float*  mst    = (float*)(ws + OFF_MST);
  float*  decays = (float*)(ws + OFF_DEC);
  float*  mendb  = (float*)(ws + OFF_MEND);
  float*  ngbuf  = (float*)(ws + OFF_NG);
  float*  nst    = (float*)(ws + OFF_NST);
  bf16_t* wifT   = (bf16_t*)(ws + OFF_WIFT);
  bf16_t* CstB   = (bf16_t*)(ws + OFF_CSTB);
  float*  htbuf  = (float*)(ws + OFF_HT);
  bf16_t* Gbuf   = (bf16_t*)(ws + OFF_G);
  bf16_t* gbuf   = (bf16_t*)(ws + OFF_GATED);
  bf16_t* ybuf   = (bf16_t*)(ws + OFF_Y);

  dim3 tb(32, 8);
  transpose_cast<<<dim3(Isz / 32, Dsz / 32), tb, 0, stream>>>(W_up, wupT, Dsz, Isz, 1.f);
  transpose_cast<<<dim3(512 / 32, Isz / 32), tb, 0, stream>>>(Wq, wqkvoT,                    Isz, 512, 1.f);
  transpose_cast<<<dim3(512 / 32, Isz / 32), tb, 0, stream>>>(Wk, wqkvoT + (size_t)512*Isz,  Isz, 512, 0.125f);
  transpose_cast<<<dim3(512 / 32, Isz / 32), tb, 0, stream>>>(Wv, wqkvoT + (size_t)1024*Isz, Isz, 512, 1.f);
  transpose_cast<<<dim3(512 / 32, Isz / 32), tb, 0, stream>>>(Wo, wqkvoT + (size_t)1536*Isz, Isz, 512, 1.f);
  transpose_cast<<<dim3(Isz / 32, 512 / 32), tb, 0, stream>>>(W_out, woutT, 512, Isz, 1.f);
  transpose_cast<<<dim3(Dsz / 32, Isz / 32), tb, 0, stream>>>(W_down, wdownT, Isz, Dsz, 1.f);
  build_wift<<<96, 256, 0, stream>>>(Wi, Wf, wifT);

  ln_kernel<<<NTOK, 256, 0, stream>>>(x, ln_g, ln_b, hbuf);

  gemm256<0><<<dim3(Isz / 256, NTOK / 256), 512, 0, stream>>>(hbuf, wupT, ubuf, nullptr, NTOK, Isz, Dsz);
  gemm256<4><<<dim3(2048 / 256, NTOK / 256), 512, 0, stream>>>(ubuf, wqkvoT, qkvob, bo, NTOK, 2048, Isz);

  ifproj_mfma<<<NTOK / 128, 256, 0, stream>>>(ubuf, wifT, bi, bfv, ifb);
  kv_transpose<<<NBH * NCH, 256, 0, stream>>>(qkvob, kTg, vTg);

  gates_a<<<NBH * NCH, 64, 0, stream>>>(ifb, bloc, Mh);
  gates_b<<<1, 32, 0, stream>>>(bloc, Mh, mst, decays, mendb);
  chunk_inc_mfma<<<NBH * NCH, 256, 0, stream>>>(kTg, vTg, ifb, bloc, mendb, Gbuf, ngbuf);
  state_scan<<<520, 256, 0, stream>>>(Gbuf, ngbuf, decays, CstB, nst);
  intra_mfma<<<NBH * NCH, 256, 0, stream>>>(qkvob, vTg, CstB, nst, ifb, bloc, Mh, mst, htbuf);

  gn_gate<<<NTOK * Hn / 4, 256, 0, stream>>>(htbuf, qkvob, mh_g, gbuf);
  gemm256<0><<<dim3(Isz / 256, NTOK / 256), 512, 0, stream>>>(gbuf, woutT, ybuf, nullptr, NTOK, Isz, 512);
  gemm_bt<3><<<dim3(Dsz / 128, NTOK / 128), 256, 0, stream>>>(ybuf, wdownT, (float*)d_out, x, NTOK, Dsz, Isz);
}